// Round 1
// baseline (836.312 us; speedup 1.0000x reference)
//
#include <hip/hip_runtime.h>
#include <math.h>

#define NPG 54
#define EPG 144
#define GLOB 10
#define KPAD 240   // 216 embeds + 10 global + 14 zero pad (16B-aligned rows)

// ---------------------------------------------------------------------------
// Kernel 1: one wave (64 threads) per graph. Full conv1+conv2+global-MLP in
// LDS, writes the concat vector v[226] (padded to 240) to workspace.
// ---------------------------------------------------------------------------
__global__ __launch_bounds__(64) void graph_kernel(
    const float* __restrict__ x,          // [B*54, 8]
    const int*   __restrict__ edge_index, // [2, E]
    const float* __restrict__ edge_attr,  // [E]
    const float* __restrict__ globalFeats,// [B, 10]
    const float* __restrict__ W_rel1, const float* __restrict__ b1,
    const float* __restrict__ W_root1,
    const float* __restrict__ W_rel2, const float* __restrict__ b2,
    const float* __restrict__ W_root2,
    const float* __restrict__ Wg1, const float* __restrict__ bg1,
    const float* __restrict__ Wg2, const float* __restrict__ bg2,
    const float* __restrict__ Wg3, const float* __restrict__ bg3,
    float* __restrict__ v_out,            // [B, KPAD]
    int E_total)
{
    __shared__ float s_x[NPG * 8];        // 432
    __shared__ int   s_src[EPG];
    __shared__ int   s_dst[EPG];
    __shared__ float s_attr[EPG];
    __shared__ float s_agg[NPG * 16];     // reused: [54][8] conv1, [54][16] conv2
    __shared__ float s_h1[NPG * 16];
    __shared__ float s_h2[NPG * 4];
    __shared__ float s_Wrel1[128], s_Wroot1[128], s_b1[16];
    __shared__ float s_Wrel2[64],  s_Wroot2[64],  s_b2[4];
    __shared__ float s_gin[GLOB], s_t1[8], s_t2[8], s_g[GLOB];

    const int g   = blockIdx.x;
    const int tid = threadIdx.x;
    const int nbase = g * NPG;
    const int ebase = g * EPG;

    // ---- stage weights + inputs ----
    for (int i = tid; i < 128; i += 64) {
        s_Wrel1[i]  = W_rel1[i];
        s_Wroot1[i] = W_root1[i];
    }
    s_Wrel2[tid]  = W_rel2[tid];    // tid < 64 always
    s_Wroot2[tid] = W_root2[tid];
    if (tid < 16) s_b1[tid] = b1[tid];
    if (tid < 4)  s_b2[tid] = b2[tid];

    const float* xg = x + (size_t)nbase * 8;
    for (int i = tid; i < NPG * 8; i += 64) {
        s_x[i]   = xg[i];
        s_agg[i] = 0.0f;              // zero conv1 accumulator [54][8]
    }
    for (int i = tid; i < EPG; i += 64) {
        s_src[i]  = edge_index[ebase + i] - nbase;
        s_dst[i]  = edge_index[E_total + ebase + i] - nbase;
        s_attr[i] = edge_attr[ebase + i];
    }
    if (tid < GLOB) s_gin[tid] = globalFeats[(size_t)g * GLOB + tid];
    __syncthreads();

    // ---- global MLP layer 1 (independent of convs) ----
    if (tid < 8) {
        float a = bg1[tid];
        #pragma unroll
        for (int i = 0; i < GLOB; i++) a += s_gin[i] * Wg1[i * 8 + tid];
        s_t1[tid] = fmaxf(a, 0.0f);
    }

    // ---- conv1 scatter: agg[dst][f] += attr * x[src][f] ----
    for (int it = tid; it < EPG * 8; it += 64) {
        int e = it >> 3, f = it & 7;
        atomicAdd(&s_agg[s_dst[e] * 8 + f], s_attr[e] * s_x[s_src[e] * 8 + f]);
    }
    __syncthreads();

    // ---- h1[n][j] = relu(b1 + agg@Wrel1 + x@Wroot1), thread n<54 ----
    if (tid < NPG) {
        float acc[16];
        #pragma unroll
        for (int j = 0; j < 16; j++) acc[j] = s_b1[j];
        #pragma unroll
        for (int i = 0; i < 8; i++) {
            float a  = s_agg[tid * 8 + i];
            float xv = s_x[tid * 8 + i];
            #pragma unroll
            for (int j = 0; j < 16; j++)
                acc[j] += a * s_Wrel1[i * 16 + j] + xv * s_Wroot1[i * 16 + j];
        }
        #pragma unroll
        for (int j = 0; j < 16; j++) s_h1[tid * 16 + j] = fmaxf(acc[j], 0.0f);
    }
    __syncthreads();

    // ---- zero conv2 accumulator + global MLP layer 2 ----
    for (int i = tid; i < NPG * 16; i += 64) s_agg[i] = 0.0f;
    if (tid < 8) {
        float a = bg2[tid];
        #pragma unroll
        for (int i = 0; i < 8; i++) a += s_t1[i] * Wg2[i * 8 + tid];
        s_t2[tid] = fmaxf(a, 0.0f);
    }
    __syncthreads();

    // ---- conv2 scatter: agg[dst][f] += attr * h1[src][f] (16 feats) ----
    for (int it = tid; it < EPG * 16; it += 64) {
        int e = it >> 4, f = it & 15;
        atomicAdd(&s_agg[s_dst[e] * 16 + f], s_attr[e] * s_h1[s_src[e] * 16 + f]);
    }
    __syncthreads();

    // ---- h2[n][j] = relu(b2 + agg2@Wrel2 + h1@Wroot2); global MLP layer 3 ----
    if (tid < NPG) {
        float acc[4];
        #pragma unroll
        for (int j = 0; j < 4; j++) acc[j] = s_b2[j];
        #pragma unroll
        for (int i = 0; i < 16; i++) {
            float a = s_agg[tid * 16 + i];
            float h = s_h1[tid * 16 + i];
            #pragma unroll
            for (int j = 0; j < 4; j++)
                acc[j] += a * s_Wrel2[i * 4 + j] + h * s_Wroot2[i * 4 + j];
        }
        #pragma unroll
        for (int j = 0; j < 4; j++) s_h2[tid * 4 + j] = fmaxf(acc[j], 0.0f);
    } else if (tid < NPG + GLOB) {
        int j = tid - NPG;
        float a = bg3[j];
        #pragma unroll
        for (int i = 0; i < 8; i++) a += s_t2[i] * Wg3[i * GLOB + j];
        s_g[j] = fmaxf(a, 0.0f);
    }
    __syncthreads();

    // ---- write v row: [embeds(216) | g(10) | zeros(14)] ----
    float* vg = v_out + (size_t)g * KPAD;
    for (int i = tid; i < KPAD; i += 64) {
        float val = 0.0f;
        if (i < 216)      val = s_h2[i];
        else if (i < 226) val = s_g[i - 216];
        vg[i] = val;
    }
}

// ---------------------------------------------------------------------------
// Kernel 2: fused out-MLP. Tiled fp32 GEMM [B,226]@[226,128] with
// bias+relu+Wo2-dot+sigmoid epilogue -> out[B].
// BM=64 rows, BN=128 (full width), BK=16, 256 threads, 4x8 acc per thread.
// ---------------------------------------------------------------------------
#define BM 64
#define BN 128
#define BK 16

__global__ __launch_bounds__(256) void out_mlp_kernel(
    const float* __restrict__ V,    // [B, KPAD] (K-pad zero-filled)
    const float* __restrict__ Wo1,  // [226, 128]
    const float* __restrict__ bo1,  // [128]
    const float* __restrict__ Wo2,  // [128]
    const float* __restrict__ bo2,  // [1]
    float* __restrict__ out)        // [B]
{
    __shared__ float As[BK][BM];        // 4 KB
    __shared__ float Bs[BK][BN];        // 8 KB
    __shared__ float s_bo1[128], s_wo2[128];
    __shared__ float red[BM][17];       // +1 pad

    const int tid  = threadIdx.x;
    const int row0 = blockIdx.x * BM;
    const int tx   = tid & 15;          // col group: 8 cols each
    const int ty   = tid >> 4;          // row group: 4 rows each

    if (tid < 128) { s_bo1[tid] = bo1[tid]; s_wo2[tid] = Wo2[tid]; }

    float acc[4][8];
    #pragma unroll
    for (int r = 0; r < 4; r++)
        #pragma unroll
        for (int c = 0; c < 8; c++) acc[r][c] = 0.0f;

    for (int k0 = 0; k0 < KPAD; k0 += BK) {
        __syncthreads();
        // load A tile: thread -> (row = tid>>2, kq = tid&3), float4 along K
        {
            int r  = tid >> 2;
            int kq = tid & 3;
            const float4 a4 = *(const float4*)(V + (size_t)(row0 + r) * KPAD + k0 + kq * 4);
            As[kq * 4 + 0][r] = a4.x;
            As[kq * 4 + 1][r] = a4.y;
            As[kq * 4 + 2][r] = a4.z;
            As[kq * 4 + 3][r] = a4.w;
        }
        // load B tile: 2048 floats = 512 float4, 2 per thread
        #pragma unroll
        for (int p = 0; p < 2; p++) {
            int id = tid + p * 256;
            int k  = id >> 5;
            int nq = id & 31;
            float4 b4 = make_float4(0.f, 0.f, 0.f, 0.f);
            if (k0 + k < 226)
                b4 = *(const float4*)(Wo1 + (size_t)(k0 + k) * 128 + nq * 4);
            *(float4*)&Bs[k][nq * 4] = b4;
        }
        __syncthreads();
        #pragma unroll
        for (int k = 0; k < BK; k++) {
            float4 a4  = *(const float4*)&As[k][ty * 4];
            float4 b40 = *(const float4*)&Bs[k][tx * 8];
            float4 b41 = *(const float4*)&Bs[k][tx * 8 + 4];
            float a[4] = {a4.x, a4.y, a4.z, a4.w};
            float b[8] = {b40.x, b40.y, b40.z, b40.w, b41.x, b41.y, b41.z, b41.w};
            #pragma unroll
            for (int r = 0; r < 4; r++)
                #pragma unroll
                for (int c = 0; c < 8; c++) acc[r][c] += a[r] * b[c];
        }
    }

    // epilogue: bias + relu + dot with Wo2 (per-thread partial over 8 cols)
    float part[4];
    #pragma unroll
    for (int r = 0; r < 4; r++) {
        float s = 0.0f;
        #pragma unroll
        for (int c = 0; c < 8; c++) {
            int col = tx * 8 + c;
            float o = fmaxf(acc[r][c] + s_bo1[col], 0.0f);
            s += o * s_wo2[col];
        }
        part[r] = s;
    }
    #pragma unroll
    for (int r = 0; r < 4; r++) red[ty * 4 + r][tx] = part[r];
    __syncthreads();
    if (tid < BM) {
        float s = bo2[0];
        #pragma unroll
        for (int i = 0; i < 16; i++) s += red[tid][i];
        out[row0 + tid] = 1.0f / (1.0f + expf(-s));
    }
}

// ---------------------------------------------------------------------------
extern "C" void kernel_launch(void* const* d_in, const int* in_sizes, int n_in,
                              void* d_out, int out_size, void* d_ws, size_t ws_size,
                              hipStream_t stream) {
    const float* x        = (const float*)d_in[0];
    const int*   ei       = (const int*)  d_in[1];
    const float* ea       = (const float*)d_in[2];
    const float* gf       = (const float*)d_in[3];
    const float* W_rel1   = (const float*)d_in[4];
    const float* b1       = (const float*)d_in[5];
    const float* W_root1  = (const float*)d_in[6];
    const float* W_rel2   = (const float*)d_in[7];
    const float* b2       = (const float*)d_in[8];
    const float* W_root2  = (const float*)d_in[9];
    const float* Wg1      = (const float*)d_in[10];
    const float* bg1      = (const float*)d_in[11];
    const float* Wg2      = (const float*)d_in[12];
    const float* bg2      = (const float*)d_in[13];
    const float* Wg3      = (const float*)d_in[14];
    const float* bg3      = (const float*)d_in[15];
    const float* Wo1      = (const float*)d_in[16];
    const float* bo1      = (const float*)d_in[17];
    const float* Wo2      = (const float*)d_in[18];
    const float* bo2      = (const float*)d_in[19];
    // d_in[20] = isTrain (eval -> dropout is identity, unused)

    float* out = (float*)d_out;
    float* V   = (float*)d_ws;             // [B, KPAD] floats

    const int B = out_size;                // 32768 graphs
    const int E = in_sizes[1] / 2;         // directed edges

    graph_kernel<<<B, 64, 0, stream>>>(
        x, ei, ea, gf,
        W_rel1, b1, W_root1, W_rel2, b2, W_root2,
        Wg1, bg1, Wg2, bg2, Wg3, bg3,
        V, E);

    out_mlp_kernel<<<B / BM, 256, 0, stream>>>(V, Wo1, bo1, Wo2, bo2, out);
}

// Round 2
// 422.114 us; speedup vs baseline: 1.9812x; 1.9812x over previous
//
#include <hip/hip_runtime.h>
#include <math.h>

#define NPG 54
#define EPG 144
#define GLOB 10
#define KPAD 240   // 216 embeds + 10 global + 14 zero pad
#define GPB 4      // graphs (waves) per block
#define XS  56     // node stride for feature-major LDS arrays

// ---------------------------------------------------------------------------
// Kernel 1: one WAVE per graph, 4 graphs per 256-thread block.
// Atomic-free (fp32) aggregation: CSR built with native int LDS atomics,
// then register-accumulated gathers. Feature-major LDS -> no bank conflicts.
// Node matmuls in registers with scalar (wave-uniform) weight loads.
// ---------------------------------------------------------------------------
struct GLds {
    float xt[8][XS];      // x transposed   [feat][node]
    float h1t[16][XS];    // h1 transposed  [feat][node]
    int   esrc[EPG];      // edge src, sorted by dst
    float eattr[EPG];     // edge attr, sorted by dst
    int   off[NPG + 1];   // CSR offsets
    int   pos[NPG];       // counts / running positions
};

__global__ __launch_bounds__(256, 5) void graph_kernel(
    const float* __restrict__ x,           // [B*54, 8]
    const int*   __restrict__ edge_index,  // [2, E]
    const float* __restrict__ edge_attr,   // [E]
    const float* __restrict__ globalFeats, // [B, 10]
    const float* __restrict__ W_rel1, const float* __restrict__ b1,
    const float* __restrict__ W_root1,
    const float* __restrict__ W_rel2, const float* __restrict__ b2,
    const float* __restrict__ W_root2,
    const float* __restrict__ Wg1, const float* __restrict__ bg1,
    const float* __restrict__ Wg2, const float* __restrict__ bg2,
    const float* __restrict__ Wg3, const float* __restrict__ bg3,
    float* __restrict__ v_out,             // [B, KPAD]
    int E_total)
{
    __shared__ GLds S[GPB];
    const int w    = threadIdx.x >> 6;
    const int lane = threadIdx.x & 63;
    const int g    = blockIdx.x * GPB + w;
    GLds& L = S[w];
    const int nbase = g * NPG;
    const int ebase = g * EPG;

    // ---- zero degree counts ----
    if (lane < NPG) L.pos[lane] = 0;

    // ---- load this graph's edges into registers (<=3 per lane) ----
    int   esrc_r[3], edst_r[3];
    float eattr_r[3];
    #pragma unroll
    for (int k = 0; k < 3; k++) {
        int e = lane + 64 * k;
        if (e < EPG) {
            esrc_r[k]  = edge_index[ebase + e] - nbase;
            edst_r[k]  = edge_index[(size_t)E_total + ebase + e] - nbase;
            eattr_r[k] = edge_attr[ebase + e];
        } else { esrc_r[k] = 0; edst_r[k] = -1; eattr_r[k] = 0.0f; }
    }

    // ---- stage x feature-major ----
    {
        const float4* xg4 = (const float4*)(x + (size_t)nbase * 8);
        #pragma unroll
        for (int k = 0; k < 2; k++) {
            int q = lane + 64 * k;
            if (q < NPG * 2) {
                float4 v = xg4[q];
                int n = q >> 1, fb = (q & 1) * 4;
                L.xt[fb + 0][n] = v.x; L.xt[fb + 1][n] = v.y;
                L.xt[fb + 2][n] = v.z; L.xt[fb + 3][n] = v.w;
            }
        }
    }
    __syncthreads();

    // ---- count degrees (native int LDS atomics) ----
    #pragma unroll
    for (int k = 0; k < 3; k++)
        if (edst_r[k] >= 0) atomicAdd(&L.pos[edst_r[k]], 1);
    __syncthreads();

    // ---- exclusive scan -> CSR offsets ----
    {
        int v = (lane < NPG) ? L.pos[lane] : 0;
        int incl = v;
        #pragma unroll
        for (int d = 1; d < 64; d <<= 1) {
            int t = __shfl_up(incl, d);
            if (lane >= d) incl += t;
        }
        if (lane < NPG) L.off[lane + 1] = incl;
        if (lane == 0)  L.off[0] = 0;
    }
    __syncthreads();
    if (lane < NPG) L.pos[lane] = L.off[lane];
    __syncthreads();

    // ---- scatter edges sorted by dst ----
    #pragma unroll
    for (int k = 0; k < 3; k++)
        if (edst_r[k] >= 0) {
            int p = atomicAdd(&L.pos[edst_r[k]], 1);
            L.esrc[p]  = esrc_r[k];
            L.eattr[p] = eattr_r[k];
        }

    // ---- global MLP (register/shuffle only, no LDS) ----
    float gout;
    {
        float gin  = (lane < GLOB) ? globalFeats[(size_t)g * GLOB + lane] : 0.0f;
        float wv1  = (lane < 80) ? Wg1[lane] : 0.0f;   // [10][8]
        float wv2  = Wg2[lane];                        // [8][8] = 64
        float wv3a = Wg3[lane];                        // [8][10] = 80: first 64
        float wv3b = (lane < 16) ? Wg3[64 + lane] : 0.0f;

        float a = (lane < 8) ? bg1[lane] : 0.0f;
        #pragma unroll
        for (int i = 0; i < GLOB; i++)
            a += __shfl(gin, i) * __shfl(wv1, (i * 8 + lane) & 63);
        float t1 = fmaxf(a, 0.0f);                     // valid lanes 0..7

        float bacc = (lane < 8) ? bg2[lane] : 0.0f;
        #pragma unroll
        for (int i = 0; i < 8; i++)
            bacc += __shfl(t1, i) * __shfl(wv2, (i * 8 + lane) & 63);
        float t2 = fmaxf(bacc, 0.0f);                  // valid lanes 0..7

        float c = (lane < GLOB) ? bg3[lane] : 0.0f;
        #pragma unroll
        for (int i = 0; i < 8; i++) {
            int idx = i * GLOB + lane;                 // valid lanes: idx <= 79
            float wlo = __shfl(wv3a, idx & 63);
            float whi = __shfl(wv3b, idx & 63);        // idx-64 == (idx&63) for idx<128
            c += __shfl(t2, i) * ((idx < 64) ? wlo : whi);
        }
        gout = fmaxf(c, 0.0f);                         // valid lanes 0..9
    }
    __syncthreads();   // edges sorted + xt staged visible

    // ---- conv1: gather into registers, lane = node ----
    const int  n   = lane;
    const bool act = (n < NPG);
    const int  e0  = act ? L.off[n]     : 0;
    const int  e1  = act ? L.off[n + 1] : 0;

    float acc[8];
    #pragma unroll
    for (int f = 0; f < 8; f++) acc[f] = 0.0f;
    for (int e = e0; e < e1; e++) {
        int s = L.esrc[e];
        float a = L.eattr[e];
        #pragma unroll
        for (int f = 0; f < 8; f++) acc[f] += a * L.xt[f][s];
    }
    float xo[8];
    #pragma unroll
    for (int f = 0; f < 8; f++) xo[f] = act ? L.xt[f][n] : 0.0f;

    // h1 = relu(b1 + acc@Wrel1 + xo@Wroot1)  (weights: scalar loads)
    float h1[16];
    #pragma unroll
    for (int j = 0; j < 16; j++) h1[j] = b1[j];
    #pragma unroll
    for (int i = 0; i < 8; i++) {
        #pragma unroll
        for (int j = 0; j < 16; j++)
            h1[j] += acc[i] * W_rel1[i * 16 + j] + xo[i] * W_root1[i * 16 + j];
    }
    #pragma unroll
    for (int j = 0; j < 16; j++) {
        h1[j] = fmaxf(h1[j], 0.0f);
        if (act) L.h1t[j][n] = h1[j];
    }
    __syncthreads();

    // ---- conv2: gather + matmul in registers ----
    float acc2[16];
    #pragma unroll
    for (int f = 0; f < 16; f++) acc2[f] = 0.0f;
    for (int e = e0; e < e1; e++) {
        int s = L.esrc[e];
        float a = L.eattr[e];
        #pragma unroll
        for (int f = 0; f < 16; f++) acc2[f] += a * L.h1t[f][s];
    }
    float h2[4];
    #pragma unroll
    for (int j = 0; j < 4; j++) h2[j] = b2[j];
    #pragma unroll
    for (int i = 0; i < 16; i++) {
        #pragma unroll
        for (int j = 0; j < 4; j++)
            h2[j] += acc2[i] * W_rel2[i * 4 + j] + h1[i] * W_root2[i * 4 + j];
    }

    // ---- write V row: [embeds 216 | g 10 | zeros 14] ----
    float* vg = v_out + (size_t)g * KPAD;
    if (act) {
        float4 o = make_float4(fmaxf(h2[0], 0.0f), fmaxf(h2[1], 0.0f),
                               fmaxf(h2[2], 0.0f), fmaxf(h2[3], 0.0f));
        *(float4*)(vg + n * 4) = o;
    }
    if (lane < GLOB)                 vg[216 + lane] = gout;
    else if (lane < 24)              vg[216 + lane] = 0.0f;   // 226..239
}

// ---------------------------------------------------------------------------
// Kernel 2: fused out-MLP GEMM [B,240]@[240,128] + bias/relu/Wo2-dot/sigmoid.
// BM=32 (1024 blocks -> 16 waves/CU), register-prefetch pipelined K-loop.
// ---------------------------------------------------------------------------
#define BM 32
#define BN 128
#define BK 16
#define KTILES (KPAD / BK)

__global__ __launch_bounds__(256) void out_mlp_kernel(
    const float* __restrict__ V,    // [B, KPAD]
    const float* __restrict__ Wo1,  // [226, 128]
    const float* __restrict__ bo1,  // [128]
    const float* __restrict__ Wo2,  // [128]
    const float* __restrict__ bo2,  // [1]
    float* __restrict__ out)        // [B]
{
    __shared__ float As[BK][BM];     // 2 KB
    __shared__ float Bs[BK][BN];     // 8 KB
    __shared__ float s_bo1[128], s_wo2[128];
    __shared__ float red[BM][17];

    const int tid  = threadIdx.x;
    const int row0 = blockIdx.x * BM;
    const int tx   = tid & 15;       // 8 cols each
    const int ty   = tid >> 4;       // 2 rows each

    if (tid < 128) { s_bo1[tid] = bo1[tid]; s_wo2[tid] = Wo2[tid]; }

    // A-load role (tid < 128): r = tid>>2 (0..31), kq = tid&3
    const int ar = tid >> 2, akq = tid & 3;
    // B-load role: 2 float4 per thread
    float4 a_reg = make_float4(0.f, 0.f, 0.f, 0.f);
    float4 b_reg[2];

    auto load_tiles = [&](int k0) {
        if (tid < 128)
            a_reg = *(const float4*)(V + (size_t)(row0 + ar) * KPAD + k0 + akq * 4);
        #pragma unroll
        for (int p = 0; p < 2; p++) {
            int id = tid + p * 256;
            int k  = id >> 5;
            int nq = id & 31;
            b_reg[p] = make_float4(0.f, 0.f, 0.f, 0.f);
            if (k0 + k < 226)
                b_reg[p] = *(const float4*)(Wo1 + (size_t)(k0 + k) * 128 + nq * 4);
        }
    };

    float acc[2][8];
    #pragma unroll
    for (int r = 0; r < 2; r++)
        #pragma unroll
        for (int c = 0; c < 8; c++) acc[r][c] = 0.0f;

    load_tiles(0);

    for (int t = 0; t < KTILES; t++) {
        __syncthreads();
        if (tid < 128) {
            As[akq * 4 + 0][ar] = a_reg.x;
            As[akq * 4 + 1][ar] = a_reg.y;
            As[akq * 4 + 2][ar] = a_reg.z;
            As[akq * 4 + 3][ar] = a_reg.w;
        }
        #pragma unroll
        for (int p = 0; p < 2; p++) {
            int id = tid + p * 256;
            *(float4*)&Bs[id >> 5][(id & 31) * 4] = b_reg[p];
        }
        __syncthreads();
        if (t + 1 < KTILES) load_tiles((t + 1) * BK);
        #pragma unroll
        for (int k = 0; k < BK; k++) {
            float2 a2  = *(const float2*)&As[k][ty * 2];
            float4 b40 = *(const float4*)&Bs[k][tx * 8];
            float4 b41 = *(const float4*)&Bs[k][tx * 8 + 4];
            float av[2] = {a2.x, a2.y};
            float bv[8] = {b40.x, b40.y, b40.z, b40.w, b41.x, b41.y, b41.z, b41.w};
            #pragma unroll
            for (int r = 0; r < 2; r++)
                #pragma unroll
                for (int c = 0; c < 8; c++) acc[r][c] += av[r] * bv[c];
        }
    }

    // epilogue: bias + relu + Wo2 partial dot
    #pragma unroll
    for (int r = 0; r < 2; r++) {
        float s = 0.0f;
        #pragma unroll
        for (int c = 0; c < 8; c++) {
            int col = tx * 8 + c;
            float o = fmaxf(acc[r][c] + s_bo1[col], 0.0f);
            s += o * s_wo2[col];
        }
        red[ty * 2 + r][tx] = s;
    }
    __syncthreads();
    if (tid < BM) {
        float s = bo2[0];
        #pragma unroll
        for (int i = 0; i < 16; i++) s += red[tid][i];
        out[row0 + tid] = 1.0f / (1.0f + expf(-s));
    }
}

// ---------------------------------------------------------------------------
extern "C" void kernel_launch(void* const* d_in, const int* in_sizes, int n_in,
                              void* d_out, int out_size, void* d_ws, size_t ws_size,
                              hipStream_t stream) {
    const float* x        = (const float*)d_in[0];
    const int*   ei       = (const int*)  d_in[1];
    const float* ea       = (const float*)d_in[2];
    const float* gf       = (const float*)d_in[3];
    const float* W_rel1   = (const float*)d_in[4];
    const float* b1       = (const float*)d_in[5];
    const float* W_root1  = (const float*)d_in[6];
    const float* W_rel2   = (const float*)d_in[7];
    const float* b2       = (const float*)d_in[8];
    const float* W_root2  = (const float*)d_in[9];
    const float* Wg1      = (const float*)d_in[10];
    const float* bg1      = (const float*)d_in[11];
    const float* Wg2      = (const float*)d_in[12];
    const float* bg2      = (const float*)d_in[13];
    const float* Wg3      = (const float*)d_in[14];
    const float* bg3      = (const float*)d_in[15];
    const float* Wo1      = (const float*)d_in[16];
    const float* bo1      = (const float*)d_in[17];
    const float* Wo2      = (const float*)d_in[18];
    const float* bo2      = (const float*)d_in[19];

    float* out = (float*)d_out;
    float* V   = (float*)d_ws;            // [B, KPAD]

    const int B = out_size;               // 32768
    const int E = in_sizes[1] / 2;

    graph_kernel<<<B / GPB, 256, 0, stream>>>(
        x, ei, ea, gf,
        W_rel1, b1, W_root1, W_rel2, b2, W_root2,
        Wg1, bg1, Wg2, bg2, Wg3, bg3,
        V, E);

    out_mlp_kernel<<<B / BM, 256, 0, stream>>>(V, Wo1, bo1, Wo2, bo2, out);
}

// Round 3
// 372.082 us; speedup vs baseline: 2.2477x; 1.1345x over previous
//
#include <hip/hip_runtime.h>
#include <math.h>

#define NPG 54
#define EPG 144
#define GLOB 10
#define KPAD 256   // V row: 216 embeds + 10 global + 30 zero pad (bf16)
#define GPB 4      // graphs (waves) per block in graph_kernel
#define XS  56     // node stride for feature-major LDS arrays

typedef short  s8x  __attribute__((ext_vector_type(8)));   // 8 bf16 (4 VGPRs)
typedef float  f32x4 __attribute__((ext_vector_type(4)));  // MFMA acc

__device__ inline unsigned short f2bf(float f) {
    unsigned u = __builtin_bit_cast(unsigned, f);
    unsigned r = (u + 0x7FFFu + ((u >> 16) & 1u)) >> 16;   // RNE
    return (unsigned short)r;
}

// ---------------------------------------------------------------------------
// Kernel 1: one WAVE per graph, 4 graphs per 256-thread block.
// CSR built with int LDS atomics, register-accumulated gathers,
// feature-major LDS. Writes V rows as bf16 [B, 256].
// ---------------------------------------------------------------------------
struct GLds {
    float xt[8][XS];      // x transposed   [feat][node]
    float h1t[16][XS];    // h1 transposed  [feat][node]
    int   esrc[EPG];
    float eattr[EPG];
    int   off[NPG + 1];
    int   pos[NPG];
};

__global__ __launch_bounds__(256, 5) void graph_kernel(
    const float* __restrict__ x,
    const int*   __restrict__ edge_index,
    const float* __restrict__ edge_attr,
    const float* __restrict__ globalFeats,
    const float* __restrict__ W_rel1, const float* __restrict__ b1,
    const float* __restrict__ W_root1,
    const float* __restrict__ W_rel2, const float* __restrict__ b2,
    const float* __restrict__ W_root2,
    const float* __restrict__ Wg1, const float* __restrict__ bg1,
    const float* __restrict__ Wg2, const float* __restrict__ bg2,
    const float* __restrict__ Wg3, const float* __restrict__ bg3,
    unsigned short* __restrict__ v_out,   // [B, KPAD] bf16
    int E_total)
{
    __shared__ GLds S[GPB];
    const int w    = threadIdx.x >> 6;
    const int lane = threadIdx.x & 63;
    const int g    = blockIdx.x * GPB + w;
    GLds& L = S[w];
    const int nbase = g * NPG;
    const int ebase = g * EPG;

    if (lane < NPG) L.pos[lane] = 0;

    int   esrc_r[3], edst_r[3];
    float eattr_r[3];
    #pragma unroll
    for (int k = 0; k < 3; k++) {
        int e = lane + 64 * k;
        if (e < EPG) {
            esrc_r[k]  = edge_index[ebase + e] - nbase;
            edst_r[k]  = edge_index[(size_t)E_total + ebase + e] - nbase;
            eattr_r[k] = edge_attr[ebase + e];
        } else { esrc_r[k] = 0; edst_r[k] = -1; eattr_r[k] = 0.0f; }
    }

    {
        const float4* xg4 = (const float4*)(x + (size_t)nbase * 8);
        #pragma unroll
        for (int k = 0; k < 2; k++) {
            int q = lane + 64 * k;
            if (q < NPG * 2) {
                float4 v = xg4[q];
                int n = q >> 1, fb = (q & 1) * 4;
                L.xt[fb + 0][n] = v.x; L.xt[fb + 1][n] = v.y;
                L.xt[fb + 2][n] = v.z; L.xt[fb + 3][n] = v.w;
            }
        }
    }
    __syncthreads();

    #pragma unroll
    for (int k = 0; k < 3; k++)
        if (edst_r[k] >= 0) atomicAdd(&L.pos[edst_r[k]], 1);
    __syncthreads();

    {
        int v = (lane < NPG) ? L.pos[lane] : 0;
        int incl = v;
        #pragma unroll
        for (int d = 1; d < 64; d <<= 1) {
            int t = __shfl_up(incl, d);
            if (lane >= d) incl += t;
        }
        if (lane < NPG) L.off[lane + 1] = incl;
        if (lane == 0)  L.off[0] = 0;
    }
    __syncthreads();
    if (lane < NPG) L.pos[lane] = L.off[lane];
    __syncthreads();

    #pragma unroll
    for (int k = 0; k < 3; k++)
        if (edst_r[k] >= 0) {
            int p = atomicAdd(&L.pos[edst_r[k]], 1);
            L.esrc[p]  = esrc_r[k];
            L.eattr[p] = eattr_r[k];
        }

    // ---- global MLP (register/shuffle only) ----
    float gout;
    {
        float gin  = (lane < GLOB) ? globalFeats[(size_t)g * GLOB + lane] : 0.0f;
        float wv1  = (lane < 80) ? Wg1[lane] : 0.0f;
        float wv2  = Wg2[lane];
        float wv3a = Wg3[lane];
        float wv3b = (lane < 16) ? Wg3[64 + lane] : 0.0f;

        float a = (lane < 8) ? bg1[lane] : 0.0f;
        #pragma unroll
        for (int i = 0; i < GLOB; i++)
            a += __shfl(gin, i) * __shfl(wv1, (i * 8 + lane) & 63);
        float t1 = fmaxf(a, 0.0f);

        float bacc = (lane < 8) ? bg2[lane] : 0.0f;
        #pragma unroll
        for (int i = 0; i < 8; i++)
            bacc += __shfl(t1, i) * __shfl(wv2, (i * 8 + lane) & 63);
        float t2 = fmaxf(bacc, 0.0f);

        float c = (lane < GLOB) ? bg3[lane] : 0.0f;
        #pragma unroll
        for (int i = 0; i < 8; i++) {
            int idx = i * GLOB + lane;
            float wlo = __shfl(wv3a, idx & 63);
            float whi = __shfl(wv3b, idx & 63);
            c += __shfl(t2, i) * ((idx < 64) ? wlo : whi);
        }
        gout = fmaxf(c, 0.0f);
    }
    __syncthreads();

    // ---- conv1 gather + lin ----
    const int  n   = lane;
    const bool act = (n < NPG);
    const int  e0  = act ? L.off[n]     : 0;
    const int  e1  = act ? L.off[n + 1] : 0;

    float acc[8];
    #pragma unroll
    for (int f = 0; f < 8; f++) acc[f] = 0.0f;
    for (int e = e0; e < e1; e++) {
        int s = L.esrc[e];
        float a = L.eattr[e];
        #pragma unroll
        for (int f = 0; f < 8; f++) acc[f] += a * L.xt[f][s];
    }
    float xo[8];
    #pragma unroll
    for (int f = 0; f < 8; f++) xo[f] = act ? L.xt[f][n] : 0.0f;

    float h1[16];
    #pragma unroll
    for (int j = 0; j < 16; j++) h1[j] = b1[j];
    #pragma unroll
    for (int i = 0; i < 8; i++) {
        #pragma unroll
        for (int j = 0; j < 16; j++)
            h1[j] += acc[i] * W_rel1[i * 16 + j] + xo[i] * W_root1[i * 16 + j];
    }
    #pragma unroll
    for (int j = 0; j < 16; j++) {
        h1[j] = fmaxf(h1[j], 0.0f);
        if (act) L.h1t[j][n] = h1[j];
    }
    __syncthreads();

    // ---- conv2 gather + lin ----
    float acc2[16];
    #pragma unroll
    for (int f = 0; f < 16; f++) acc2[f] = 0.0f;
    for (int e = e0; e < e1; e++) {
        int s = L.esrc[e];
        float a = L.eattr[e];
        #pragma unroll
        for (int f = 0; f < 16; f++) acc2[f] += a * L.h1t[f][s];
    }
    float h2[4];
    #pragma unroll
    for (int j = 0; j < 4; j++) h2[j] = b2[j];
    #pragma unroll
    for (int i = 0; i < 16; i++) {
        #pragma unroll
        for (int j = 0; j < 4; j++)
            h2[j] += acc2[i] * W_rel2[i * 4 + j] + h1[i] * W_root2[i * 4 + j];
    }

    // ---- write bf16 V row: [embeds 216 | g 10 | zeros 30] ----
    unsigned short* vg = v_out + (size_t)g * KPAD;
    if (act) {
        ushort4 o;
        o.x = f2bf(fmaxf(h2[0], 0.0f));
        o.y = f2bf(fmaxf(h2[1], 0.0f));
        o.z = f2bf(fmaxf(h2[2], 0.0f));
        o.w = f2bf(fmaxf(h2[3], 0.0f));
        *(ushort4*)(vg + n * 4) = o;
    }
    if (lane < GLOB)      vg[216 + lane] = f2bf(gout);
    else if (lane < 40)   vg[216 + lane] = 0;    // cols 226..255 = 0
}

// ---------------------------------------------------------------------------
// Kernel 2: out-MLP via bf16 MFMA.
// Grid 256 blocks (1/CU) x 512 threads (8 waves). M-tile 128, N=128, K=256.
// Wo1 converted fp32->bf16 into transposed LDS Bt[128][264] (+8 pad: 2-way
// bank aliasing only). A-fragments straight from global V (bf16). Epilogue
// (bias+relu+Wo2 dot+sigmoid) fully in registers via quad shfl_xor butterfly.
// ---------------------------------------------------------------------------
#define BTS 264   // Bt row stride in bf16 elements (528 B: %32 words = 4)

__global__ __launch_bounds__(512) void out_mlp_mfma(
    const unsigned short* __restrict__ V,   // [B, KPAD] bf16
    const float* __restrict__ Wo1,          // [226, 128] fp32
    const float* __restrict__ bo1,          // [128]
    const float* __restrict__ Wo2,          // [128]
    const float* __restrict__ bo2,          // [1]
    float* __restrict__ out)                // [B]
{
    extern __shared__ unsigned short Bt[];  // [128][BTS] = 67584 B

    const int tid  = threadIdx.x;
    const int w    = tid >> 6;          // wave 0..7 -> 16-row strip
    const int lane = tid & 63;
    const int ln15 = lane & 15;
    const int quad = lane >> 4;
    const int row0 = blockIdx.x * 128;

    // per-lane epilogue constants: col = t*16 + ln15
    float bo1v[8], wo2v[8];
    #pragma unroll
    for (int t = 0; t < 8; t++) {
        bo1v[t] = bo1[t * 16 + ln15];
        wo2v[t] = Wo2[t * 16 + ln15];
    }
    const float bo2v = bo2[0];

    // prefetch all 8 A-fragments for this wave's 16-row strip
    const unsigned short* Arow = V + (size_t)(row0 + w * 16 + ln15) * KPAD;
    s8x af[8];
    #pragma unroll
    for (int s = 0; s < 8; s++)
        af[s] = *(const s8x*)(Arow + s * 32 + quad * 8);

    // ---- zero Bt (incl. pad + k>=226), then stage Wo1 transposed bf16 ----
    {
        int4* bz = (int4*)Bt;                  // 67584/16 = 4224 int4
        for (int i = tid; i < 4224; i += 512)
            bz[i] = make_int4(0, 0, 0, 0);
    }
    __syncthreads();
    for (int i = tid; i < 7232; i += 512) {    // 226*128/4 float4s
        int k  = i >> 5;
        int nq = (i & 31) * 4;
        float4 v = *(const float4*)(Wo1 + (size_t)k * 128 + nq);
        Bt[(nq + 0) * BTS + k] = f2bf(v.x);
        Bt[(nq + 1) * BTS + k] = f2bf(v.y);
        Bt[(nq + 2) * BTS + k] = f2bf(v.z);
        Bt[(nq + 3) * BTS + k] = f2bf(v.w);
    }
    __syncthreads();

    // ---- MFMA main loop: 8 k-steps x 8 n-tiles ----
    f32x4 acc[8];
    #pragma unroll
    for (int t = 0; t < 8; t++) acc[t] = (f32x4){0.f, 0.f, 0.f, 0.f};

    for (int s = 0; s < 8; s++) {
        #pragma unroll
        for (int t = 0; t < 8; t++) {
            s8x bf = *(const s8x*)&Bt[(t * 16 + ln15) * BTS + s * 32 + quad * 8];
            acc[t] = __builtin_amdgcn_mfma_f32_16x16x32_bf16(af[s], bf, acc[t], 0, 0, 0);
        }
    }

    // ---- epilogue: D layout col=ln15, row=quad*4+reg ----
    #pragma unroll
    for (int rr = 0; rr < 4; rr++) {
        float p = 0.0f;
        #pragma unroll
        for (int t = 0; t < 8; t++) {
            float h = fmaxf(acc[t][rr] + bo1v[t], 0.0f);
            p += h * wo2v[t];
        }
        p += __shfl_xor(p, 1);
        p += __shfl_xor(p, 2);
        p += __shfl_xor(p, 4);
        p += __shfl_xor(p, 8);
        if (ln15 == rr) {
            int row = row0 + w * 16 + quad * 4 + rr;
            out[row] = 1.0f / (1.0f + expf(-(p + bo2v)));
        }
    }
}

// ---------------------------------------------------------------------------
extern "C" void kernel_launch(void* const* d_in, const int* in_sizes, int n_in,
                              void* d_out, int out_size, void* d_ws, size_t ws_size,
                              hipStream_t stream) {
    const float* x        = (const float*)d_in[0];
    const int*   ei       = (const int*)  d_in[1];
    const float* ea       = (const float*)d_in[2];
    const float* gf       = (const float*)d_in[3];
    const float* W_rel1   = (const float*)d_in[4];
    const float* b1       = (const float*)d_in[5];
    const float* W_root1  = (const float*)d_in[6];
    const float* W_rel2   = (const float*)d_in[7];
    const float* b2       = (const float*)d_in[8];
    const float* W_root2  = (const float*)d_in[9];
    const float* Wg1      = (const float*)d_in[10];
    const float* bg1      = (const float*)d_in[11];
    const float* Wg2      = (const float*)d_in[12];
    const float* bg2      = (const float*)d_in[13];
    const float* Wg3      = (const float*)d_in[14];
    const float* bg3      = (const float*)d_in[15];
    const float* Wo1      = (const float*)d_in[16];
    const float* bo1      = (const float*)d_in[17];
    const float* Wo2      = (const float*)d_in[18];
    const float* bo2      = (const float*)d_in[19];

    float* out = (float*)d_out;
    unsigned short* V = (unsigned short*)d_ws;   // [B, KPAD] bf16

    const int B = out_size;                      // 32768
    const int E = in_sizes[1] / 2;

    graph_kernel<<<B / GPB, 256, 0, stream>>>(
        x, ei, ea, gf,
        W_rel1, b1, W_root1, W_rel2, b2, W_root2,
        Wg1, bg1, Wg2, bg2, Wg3, bg3,
        V, E);

    out_mlp_mfma<<<B / 128, 512, 128 * BTS * sizeof(unsigned short), stream>>>(
        V, Wo1, bo1, Wo2, bo2, out);
}

// Round 4
// 280.379 us; speedup vs baseline: 2.9828x; 1.3271x over previous
//
#include <hip/hip_runtime.h>
#include <math.h>

#define NPG 54
#define EPG 144
#define GLOB 10
#define KPAD 256   // V row: 216 embeds + 10 global + 30 zero pad (fp16)
#define GPB 2      // graphs (waves) per block in graph_kernel

typedef _Float16 f16x8 __attribute__((ext_vector_type(8)));
typedef _Float16 f16x4 __attribute__((ext_vector_type(4)));
typedef float    f32x4 __attribute__((ext_vector_type(4)));

// ---------------------------------------------------------------------------
// Kernel 1: one WAVE per graph, 2 graphs per 128-thread block.
// Convs as dense-adjacency fp16 MFMA:
//   Adj[64][72] built from CSR-sorted edges (duplicate-safe RMW),
//   conv1 = Adj@X, lin1 = [agg1|x]@Wc1, conv2 = Adj@H1 (A-frags reused in
//   registers), lin2 = [agg2|h1]@Wc2.  All staging fp16, acc fp32.
// ---------------------------------------------------------------------------
struct __align__(16) GL {
    _Float16 Adj[64][72];   // 9216 B  row-major Adj[dst][src]
    _Float16 Xt[16][72];    // 2304 B  X^T [feat][node]; reused as vtmp at end
    _Float16 H1t[16][72];   // 2304 B  H1^T [feat][node]
    _Float16 cat[64][32];   // 4096 B  lin A staging: [agg|root] per node row
    unsigned epack[EPG];    // 576 B   attr(top 24 bits) | src(low 8)
    int      off[56];       // CSR offsets / cursors
};

__global__ __launch_bounds__(128, 2) void graph_kernel(
    const float* __restrict__ x,
    const int*   __restrict__ edge_index,
    const float* __restrict__ edge_attr,
    const float* __restrict__ W_rel1, const float* __restrict__ b1,
    const float* __restrict__ W_root1,
    const float* __restrict__ W_rel2, const float* __restrict__ b2,
    const float* __restrict__ W_root2,
    _Float16* __restrict__ v_out,     // [B, KPAD] fp16
    int E_total)
{
    __shared__ GL S[GPB];
    __shared__ _Float16 Wc1[16][40];  // [n][k] k<8:Wrel1, 8..15:Wroot1, 16..31:0
    __shared__ _Float16 Wc2[16][40];  // [n][k] k<16:Wrel2, 16..31:Wroot2 (n>=4: 0)

    const int tid  = threadIdx.x;
    const int w    = tid >> 6;
    const int lane = tid & 63;
    const int ln15 = lane & 15;
    const int quad = lane >> 4;
    const int g    = blockIdx.x * GPB + w;
    GL& L = S[w];
    const int nbase = g * NPG;
    const int ebase = g * EPG;

    // ---- build fused weight tiles (block-cooperative) ----
    for (int i = tid; i < 512; i += 128) {
        int n = i & 15, k = i >> 4;
        float v1 = (k < 8) ? W_rel1[k * 16 + n]
                 : (k < 16 ? W_root1[(k - 8) * 16 + n] : 0.0f);
        Wc1[n][k] = (_Float16)v1;
        float v2 = 0.0f;
        if (n < 4) v2 = (k < 16) ? W_rel2[k * 4 + n] : W_root2[(k - 16) * 4 + n];
        Wc2[n][k] = (_Float16)v2;
    }

    // ---- zero Adj+Xt+H1t+cat (first 17920 B of GL) + off ----
    {
        uint4* z = (uint4*)&L;
        #pragma unroll
        for (int i = lane; i < 1120; i += 64) z[i] = make_uint4(0, 0, 0, 0);
        if (lane < 56) L.off[lane] = 0;
    }

    // ---- load edges into registers (<=3 per lane) ----
    int   esrc_r[3], edst_r[3];
    unsigned ea_r[3];
    #pragma unroll
    for (int k = 0; k < 3; k++) {
        int e = lane + 64 * k;
        if (e < EPG) {
            esrc_r[k] = edge_index[ebase + e] - nbase;
            edst_r[k] = edge_index[(size_t)E_total + ebase + e] - nbase;
            ea_r[k]   = __builtin_bit_cast(unsigned, edge_attr[ebase + e]);
        } else { esrc_r[k] = 0; edst_r[k] = -1; ea_r[k] = 0; }
    }
    __syncthreads();   // zeroing complete

    // ---- stage x: cat[n][8..15] (root path) + Xt[f][n] (B operand) ----
    if (lane < NPG) {
        const float4* xg4 = (const float4*)(x + (size_t)(nbase + lane) * 8);
        float4 lo = xg4[0], hi = xg4[1];
        f16x8 xv = { (_Float16)lo.x, (_Float16)lo.y, (_Float16)lo.z, (_Float16)lo.w,
                     (_Float16)hi.x, (_Float16)hi.y, (_Float16)hi.z, (_Float16)hi.w };
        *(f16x8*)&L.cat[lane][8] = xv;
        #pragma unroll
        for (int f = 0; f < 8; f++) L.Xt[f][lane] = xv[f];
    }

    // ---- CSR: count degrees into off ----
    #pragma unroll
    for (int k = 0; k < 3; k++)
        if (edst_r[k] >= 0) atomicAdd(&L.off[edst_r[k]], 1);
    __syncthreads();

    // ---- exclusive scan over off[0..53] ----
    {
        int cnt = (lane < NPG) ? L.off[lane] : 0;
        int incl = cnt;
        #pragma unroll
        for (int d = 1; d < 64; d <<= 1) {
            int t = __shfl_up(incl, d);
            if (lane >= d) incl += t;
        }
        if (lane < NPG) L.off[lane] = incl - cnt;   // exclusive start
    }
    __syncthreads();

    // ---- scatter edges sorted by dst (off doubles as cursor) ----
    #pragma unroll
    for (int k = 0; k < 3; k++)
        if (edst_r[k] >= 0) {
            int p = atomicAdd(&L.off[edst_r[k]], 1);
            L.epack[p] = (ea_r[k] & 0xFFFFFF00u) | (unsigned)esrc_r[k];
        }
    __syncthreads();

    // ---- build Adj rows (lane = dst node; duplicate-safe serial RMW) ----
    if (lane < NPG) {
        int e1 = L.off[lane];                       // post-scatter = end(lane)
        int e0 = lane ? L.off[lane - 1] : 0;        // end(lane-1) = start(lane)
        for (int e = e0; e < e1; e++) {
            unsigned p = L.epack[e];
            int   s = p & 0xFF;
            float a = __builtin_bit_cast(float, p & 0xFFFFFF00u);
            L.Adj[lane][s] = (_Float16)((float)L.Adj[lane][s] + a);
        }
    }
    __syncthreads();

    // ---- load Adj A-fragments once, reuse for both convs ----
    f16x8 af[4][2];
    #pragma unroll
    for (int t = 0; t < 4; t++)
        #pragma unroll
        for (int ks = 0; ks < 2; ks++)
            af[t][ks] = *(const f16x8*)&L.Adj[t * 16 + ln15][ks * 32 + quad * 8];

    // ---- conv1: agg1 = Adj @ X ----
    f32x4 acc1[4];
    #pragma unroll
    for (int t = 0; t < 4; t++) acc1[t] = (f32x4){0.f, 0.f, 0.f, 0.f};
    #pragma unroll
    for (int ks = 0; ks < 2; ks++) {
        f16x8 bx = *(const f16x8*)&L.Xt[ln15][ks * 32 + quad * 8];
        #pragma unroll
        for (int t = 0; t < 4; t++)
            acc1[t] = __builtin_amdgcn_mfma_f32_16x16x32_f16(af[t][ks], bx, acc1[t], 0, 0, 0);
    }
    // write agg1 into cat cols 0..7 (C layout: col=ln15, row=quad*4+r)
    #pragma unroll
    for (int t = 0; t < 4; t++)
        #pragma unroll
        for (int r = 0; r < 4; r++)
            if (ln15 < 8) L.cat[t * 16 + quad * 4 + r][ln15] = (_Float16)acc1[t][r];
    __syncthreads();

    // ---- lin1: h1 = relu(b1 + [agg1|x] @ Wc1) ----
    const float b1v = b1[ln15];
    f32x4 accL[4];
    {
        f16x8 wc = *(const f16x8*)&Wc1[ln15][quad * 8];
        #pragma unroll
        for (int t = 0; t < 4; t++) {
            f16x8 al = *(const f16x8*)&L.cat[t * 16 + ln15][quad * 8];
            f32x4 ci = (f32x4){b1v, b1v, b1v, b1v};
            accL[t] = __builtin_amdgcn_mfma_f32_16x16x32_f16(al, wc, ci, 0, 0, 0);
        }
    }
    // relu; write H1t (B operand for conv2) + cat cols 16..31 (root for lin2)
    #pragma unroll
    for (int t = 0; t < 4; t++) {
        f16x4 hp;
        #pragma unroll
        for (int r = 0; r < 4; r++) {
            float h = fmaxf(accL[t][r], 0.0f);
            hp[r] = (_Float16)h;
            L.cat[t * 16 + quad * 4 + r][16 + ln15] = (_Float16)h;
        }
        *(f16x4*)&L.H1t[ln15][t * 16 + quad * 4] = hp;
    }
    __syncthreads();

    // ---- conv2: agg2 = Adj @ H1 (A-frags from registers) ----
    f32x4 acc2[4];
    #pragma unroll
    for (int t = 0; t < 4; t++) acc2[t] = (f32x4){0.f, 0.f, 0.f, 0.f};
    #pragma unroll
    for (int ks = 0; ks < 2; ks++) {
        f16x8 bh = *(const f16x8*)&L.H1t[ln15][ks * 32 + quad * 8];
        #pragma unroll
        for (int t = 0; t < 4; t++)
            acc2[t] = __builtin_amdgcn_mfma_f32_16x16x32_f16(af[t][ks], bh, acc2[t], 0, 0, 0);
    }
    #pragma unroll
    for (int t = 0; t < 4; t++)
        #pragma unroll
        for (int r = 0; r < 4; r++)
            L.cat[t * 16 + quad * 4 + r][ln15] = (_Float16)acc2[t][r];
    __syncthreads();

    // ---- lin2: h2 = relu(b2 + [agg2|h1] @ Wc2) ----
    const float b2v = b2[ln15 & 3];
    _Float16* vt = &L.Xt[0][0];      // Xt dead after conv1 -> reuse as vtmp[216]
    {
        f16x8 wc = *(const f16x8*)&Wc2[ln15][quad * 8];
        #pragma unroll
        for (int t = 0; t < 4; t++) {
            f16x8 a2 = *(const f16x8*)&L.cat[t * 16 + ln15][quad * 8];
            f32x4 ci = (f32x4){b2v, b2v, b2v, b2v};
            f32x4 h2 = __builtin_amdgcn_mfma_f32_16x16x32_f16(a2, wc, ci, 0, 0, 0);
            #pragma unroll
            for (int r = 0; r < 4; r++) {
                int node = t * 16 + quad * 4 + r;
                if (ln15 < 4 && node < NPG)
                    vt[node * 4 + ln15] = (_Float16)fmaxf(h2[r], 0.0f);
            }
        }
    }
    __syncthreads();

    // ---- coalesced V write: cols 0..215 (216..255 written by g_kernel) ----
    if (lane < 27)
        *(f16x8*)(v_out + (size_t)g * KPAD + lane * 8) = *(const f16x8*)&vt[lane * 8];
}

// ---------------------------------------------------------------------------
// Kernel 1b: global-feature MLP, one thread per graph. Writes V cols 216..255.
// ---------------------------------------------------------------------------
__global__ __launch_bounds__(256) void g_kernel(
    const float* __restrict__ gf,
    const float* __restrict__ Wg1, const float* __restrict__ bg1,
    const float* __restrict__ Wg2, const float* __restrict__ bg2,
    const float* __restrict__ Wg3, const float* __restrict__ bg3,
    _Float16* __restrict__ v_out)
{
    int row = blockIdx.x * 256 + threadIdx.x;
    const float* gr = gf + (size_t)row * GLOB;
    float t0[GLOB];
    #pragma unroll
    for (int i = 0; i < GLOB; i++) t0[i] = gr[i];
    float t1[8];
    #pragma unroll
    for (int j = 0; j < 8; j++) {
        float a = bg1[j];
        #pragma unroll
        for (int i = 0; i < GLOB; i++) a += t0[i] * Wg1[i * 8 + j];
        t1[j] = fmaxf(a, 0.0f);
    }
    float t2[8];
    #pragma unroll
    for (int j = 0; j < 8; j++) {
        float a = bg2[j];
        #pragma unroll
        for (int i = 0; i < 8; i++) a += t1[i] * Wg2[i * 8 + j];
        t2[j] = fmaxf(a, 0.0f);
    }
    float t3[GLOB];
    #pragma unroll
    for (int j = 0; j < GLOB; j++) {
        float a = bg3[j];
        #pragma unroll
        for (int i = 0; i < 8; i++) a += t2[i] * Wg3[i * GLOB + j];
        t3[j] = fmaxf(a, 0.0f);
    }
    _Float16* vr = v_out + (size_t)row * KPAD + 216;   // byte 432: 16B-aligned
    f16x8 v0 = { (_Float16)t3[0], (_Float16)t3[1], (_Float16)t3[2], (_Float16)t3[3],
                 (_Float16)t3[4], (_Float16)t3[5], (_Float16)t3[6], (_Float16)t3[7] };
    f16x8 v1 = { (_Float16)t3[8], (_Float16)t3[9], 0, 0, 0, 0, 0, 0 };
    f16x8 zz = { 0, 0, 0, 0, 0, 0, 0, 0 };
    *(f16x8*)(vr +  0) = v0;
    *(f16x8*)(vr +  8) = v1;
    *(f16x8*)(vr + 16) = zz;
    *(f16x8*)(vr + 24) = zz;
    *(f16x8*)(vr + 32) = zz;
}

// ---------------------------------------------------------------------------
// Kernel 2: out-MLP via fp16 MFMA (round-3 structure, bf16 -> fp16).
// ---------------------------------------------------------------------------
#define BTS 264

__global__ __launch_bounds__(512) void out_mlp_mfma(
    const _Float16* __restrict__ V,    // [B, KPAD] fp16
    const float* __restrict__ Wo1,     // [226, 128] fp32
    const float* __restrict__ bo1,
    const float* __restrict__ Wo2,
    const float* __restrict__ bo2,
    float* __restrict__ out)
{
    extern __shared__ _Float16 Bt[];   // [128][BTS] = 67584 B

    const int tid  = threadIdx.x;
    const int w    = tid >> 6;
    const int lane = tid & 63;
    const int ln15 = lane & 15;
    const int quad = lane >> 4;
    const int row0 = blockIdx.x * 128;

    float bo1v[8], wo2v[8];
    #pragma unroll
    for (int t = 0; t < 8; t++) {
        bo1v[t] = bo1[t * 16 + ln15];
        wo2v[t] = Wo2[t * 16 + ln15];
    }
    const float bo2v = bo2[0];

    const _Float16* Arow = V + (size_t)(row0 + w * 16 + ln15) * KPAD;
    f16x8 af[8];
    #pragma unroll
    for (int s = 0; s < 8; s++)
        af[s] = *(const f16x8*)(Arow + s * 32 + quad * 8);

    {
        int4* bz = (int4*)Bt;
        for (int i = tid; i < 4224; i += 512)
            bz[i] = make_int4(0, 0, 0, 0);
    }
    __syncthreads();
    for (int i = tid; i < 7232; i += 512) {
        int k  = i >> 5;
        int nq = (i & 31) * 4;
        float4 v = *(const float4*)(Wo1 + (size_t)k * 128 + nq);
        Bt[(nq + 0) * BTS + k] = (_Float16)v.x;
        Bt[(nq + 1) * BTS + k] = (_Float16)v.y;
        Bt[(nq + 2) * BTS + k] = (_Float16)v.z;
        Bt[(nq + 3) * BTS + k] = (_Float16)v.w;
    }
    __syncthreads();

    f32x4 acc[8];
    #pragma unroll
    for (int t = 0; t < 8; t++) acc[t] = (f32x4){0.f, 0.f, 0.f, 0.f};

    for (int s = 0; s < 8; s++) {
        #pragma unroll
        for (int t = 0; t < 8; t++) {
            f16x8 bf = *(const f16x8*)&Bt[(t * 16 + ln15) * BTS + s * 32 + quad * 8];
            acc[t] = __builtin_amdgcn_mfma_f32_16x16x32_f16(af[s], bf, acc[t], 0, 0, 0);
        }
    }

    #pragma unroll
    for (int rr = 0; rr < 4; rr++) {
        float p = 0.0f;
        #pragma unroll
        for (int t = 0; t < 8; t++) {
            float h = fmaxf(acc[t][rr] + bo1v[t], 0.0f);
            p += h * wo2v[t];
        }
        p += __shfl_xor(p, 1);
        p += __shfl_xor(p, 2);
        p += __shfl_xor(p, 4);
        p += __shfl_xor(p, 8);
        if (ln15 == rr) {
            int row = row0 + w * 16 + quad * 4 + rr;
            out[row] = 1.0f / (1.0f + expf(-(p + bo2v)));
        }
    }
}

// ---------------------------------------------------------------------------
extern "C" void kernel_launch(void* const* d_in, const int* in_sizes, int n_in,
                              void* d_out, int out_size, void* d_ws, size_t ws_size,
                              hipStream_t stream) {
    const float* x        = (const float*)d_in[0];
    const int*   ei       = (const int*)  d_in[1];
    const float* ea       = (const float*)d_in[2];
    const float* gf       = (const float*)d_in[3];
    const float* W_rel1   = (const float*)d_in[4];
    const float* b1       = (const float*)d_in[5];
    const float* W_root1  = (const float*)d_in[6];
    const float* W_rel2   = (const float*)d_in[7];
    const float* b2       = (const float*)d_in[8];
    const float* W_root2  = (const float*)d_in[9];
    const float* Wg1      = (const float*)d_in[10];
    const float* bg1      = (const float*)d_in[11];
    const float* Wg2      = (const float*)d_in[12];
    const float* bg2      = (const float*)d_in[13];
    const float* Wg3      = (const float*)d_in[14];
    const float* bg3      = (const float*)d_in[15];
    const float* Wo1      = (const float*)d_in[16];
    const float* bo1      = (const float*)d_in[17];
    const float* Wo2      = (const float*)d_in[18];
    const float* bo2      = (const float*)d_in[19];

    float* out   = (float*)d_out;
    _Float16* V  = (_Float16*)d_ws;             // [B, KPAD] fp16

    const int B = out_size;                     // 32768
    const int E = in_sizes[1] / 2;

    graph_kernel<<<B / GPB, 128, 0, stream>>>(
        x, ei, ea,
        W_rel1, b1, W_root1, W_rel2, b2, W_root2,
        V, E);

    g_kernel<<<B / 256, 256, 0, stream>>>(gf, Wg1, bg1, Wg2, bg2, Wg3, bg3, V);

    out_mlp_mfma<<<B / 128, 512, 128 * BTS * sizeof(_Float16), stream>>>(
        V, Wo1, bo1, Wo2, bo2, out);
}

// Round 5
// 254.460 us; speedup vs baseline: 3.2866x; 1.1019x over previous
//
#include <hip/hip_runtime.h>
#include <math.h>

#define NPG 54
#define EPG 144
#define GLOB 10
#define KPAD 256   // V row: 216 embeds + 10 global + 30 zero pad (fp16)
#define GPB 2      // graphs (waves) per block in graph_kernel

typedef _Float16 f16x8 __attribute__((ext_vector_type(8)));
typedef _Float16 f16x4 __attribute__((ext_vector_type(4)));
typedef float    f32x4 __attribute__((ext_vector_type(4)));

// intra-wave LDS fence: all this wave's DS ops complete + compiler ordering.
// (waves in a block share no LDS region -> no s_barrier needed anywhere)
#define WSYNC() asm volatile("s_waitcnt lgkmcnt(0)" ::: "memory")

__device__ inline unsigned short f2bf(float f) {
    unsigned u = __builtin_bit_cast(unsigned, f);
    return (unsigned short)((u + 0x7FFFu + ((u >> 16) & 1u)) >> 16);
}

// ---------------------------------------------------------------------------
// Kernel 1: one WAVE per graph, 2 graphs per 128-thread block, NO barriers.
// LDS per graph = 11520 B (23 KB/block -> 7 blocks/CU = 14 waves):
//   Adj[64][72] fp16 (9216 B)
//     - rows 54..63 tail also hosts epack[144] + off[56] during CSR build
//     - cat[64][40] overlays bytes 0..5119 after A-frags move to registers
//   XH[16][72] fp16 (2304 B): Xt -> H1t -> vtmp (phase-disjoint)
// Weights live in registers (B-fragment layout), staged via global loads.
// ---------------------------------------------------------------------------
struct __align__(16) GL {
    _Float16 Adj[64][72];   // 9216 B
    _Float16 XH[16][72];    // 2304 B
};

__global__ __launch_bounds__(128, 4) void graph_kernel(
    const float* __restrict__ x,
    const int*   __restrict__ edge_index,
    const float* __restrict__ edge_attr,
    const float* __restrict__ W_rel1, const float* __restrict__ b1,
    const float* __restrict__ W_root1,
    const float* __restrict__ W_rel2, const float* __restrict__ b2,
    const float* __restrict__ W_root2,
    _Float16* __restrict__ v_out,     // [B, KPAD] fp16
    int E_total)
{
    __shared__ GL S[GPB];
    const int tid  = threadIdx.x;
    const int w    = tid >> 6;
    const int lane = tid & 63;
    const int ln15 = lane & 15;
    const int quad = lane >> 4;
    const int g    = blockIdx.x * GPB + w;
    GL& L = S[w];
    const int nbase = g * NPG;
    const int ebase = g * EPG;

    _Float16 (*cat)[40] = (_Float16(*)[40])&L.Adj[0][0];       // overlay
    unsigned* epack = (unsigned*)&L.Adj[54][0];                 // 576 B
    int*      off   = (int*)((char*)&L.Adj[54][0] + 576);       // 224 B

    // ---- issue global loads FIRST (stay in flight through zeroing) ----
    int   esrc_r[3], edst_r[3];
    unsigned ea_r[3];
    #pragma unroll
    for (int k = 0; k < 3; k++) {
        int e = lane + 64 * k;
        if (e < EPG) {
            esrc_r[k] = edge_index[ebase + e] - nbase;
            edst_r[k] = edge_index[(size_t)E_total + ebase + e] - nbase;
            ea_r[k]   = __builtin_bit_cast(unsigned, edge_attr[ebase + e]);
        } else { esrc_r[k] = 0; edst_r[k] = -1; ea_r[k] = 0; }
    }
    f16x8 xv = {0, 0, 0, 0, 0, 0, 0, 0};
    if (lane < NPG) {
        const float4* xg4 = (const float4*)(x + (size_t)(nbase + lane) * 8);
        float4 lo = xg4[0], hi = xg4[1];
        xv = (f16x8){ (_Float16)lo.x, (_Float16)lo.y, (_Float16)lo.z, (_Float16)lo.w,
                      (_Float16)hi.x, (_Float16)hi.y, (_Float16)hi.z, (_Float16)hi.w };
    }

    // ---- weight B-fragments in registers (wave-uniform-ish global loads) ----
    // Wc1[k][n]: k<8 Wrel1[k][n], k<16 Wroot1[k-8][n], else 0.  n=ln15, k=quad*8+j
    f16x8 wf1 = {0, 0, 0, 0, 0, 0, 0, 0};
    if (quad == 0) {
        #pragma unroll
        for (int j = 0; j < 8; j++) wf1[j] = (_Float16)W_rel1[j * 16 + ln15];
    } else if (quad == 1) {
        #pragma unroll
        for (int j = 0; j < 8; j++) wf1[j] = (_Float16)W_root1[j * 16 + ln15];
    }
    // Wc2[k][n]: n<4: k<16 Wrel2[k][n], k<32 Wroot2[k-16][n]; n>=4: 0
    f16x8 wf2 = {0, 0, 0, 0, 0, 0, 0, 0};
    if (ln15 < 4) {
        #pragma unroll
        for (int j = 0; j < 8; j++) {
            int k = quad * 8 + j;
            wf2[j] = (_Float16)((k < 16) ? W_rel2[k * 4 + ln15]
                                         : W_root2[(k - 16) * 4 + ln15]);
        }
    }
    const float b1v = b1[ln15];
    const float b2v = b2[ln15 & 3];

    // ---- zero the whole per-graph region (incl. off) ----
    {
        uint4* z = (uint4*)&L;
        #pragma unroll
        for (int i = lane; i < 720; i += 64) z[i] = make_uint4(0, 0, 0, 0);
    }
    // stage Xt[feat][node] (B operand for conv1)
    if (lane < NPG) {
        #pragma unroll
        for (int f = 0; f < 8; f++) L.XH[f][lane] = xv[f];
    }
    WSYNC();

    // ---- CSR: degree count -> scan -> scatter (all wave-local) ----
    #pragma unroll
    for (int k = 0; k < 3; k++)
        if (edst_r[k] >= 0) atomicAdd(&off[edst_r[k]], 1);
    WSYNC();
    {
        int cnt = (lane < NPG) ? off[lane] : 0;
        int incl = cnt;
        #pragma unroll
        for (int d = 1; d < 64; d <<= 1) {
            int t = __shfl_up(incl, d);
            if (lane >= d) incl += t;
        }
        if (lane < NPG) off[lane] = incl - cnt;   // exclusive start
    }
    WSYNC();
    #pragma unroll
    for (int k = 0; k < 3; k++)
        if (edst_r[k] >= 0) {
            int p = atomicAdd(&off[edst_r[k]], 1);
            epack[p] = (ea_r[k] & 0xFFFFFF00u) | (unsigned)esrc_r[k];
        }
    WSYNC();

    // ---- build Adj row (lane = dst): merge duplicates in registers,
    //      independent reads + one write per distinct src (no RMW chain) ----
    if (lane < NPG) {
        int e1 = off[lane];
        int e0 = lane ? off[lane - 1] : 0;
        for (int e = e0; e < e1; e++) {
            unsigned p = epack[e];
            int s = p & 0xFF;
            bool first = true;
            for (int e2 = e0; e2 < e; e2++)
                if ((int)(epack[e2] & 0xFF) == s) first = false;
            if (first) {
                float a = __builtin_bit_cast(float, p & 0xFFFFFF00u);
                for (int e2 = e + 1; e2 < e1; e2++) {
                    unsigned q = epack[e2];
                    if ((int)(q & 0xFF) == s)
                        a += __builtin_bit_cast(float, q & 0xFFFFFF00u);
                }
                L.Adj[lane][s] = (_Float16)a;
            }
        }
    }
    WSYNC();

    // ---- A-fragments (Adj) -> registers; Adj LDS becomes dead ----
    f16x8 af[4][2];
    #pragma unroll
    for (int t = 0; t < 4; t++)
        #pragma unroll
        for (int ks = 0; ks < 2; ks++)
            af[t][ks] = *(const f16x8*)&L.Adj[t * 16 + ln15][ks * 32 + quad * 8];
    WSYNC();   // af in regs before cat overlay writes

    // ---- cat overlay: x-root (cols 8..15 from regs) + zeros (cols 16..31) ----
    if (lane < NPG) *(f16x8*)&cat[lane][8] = xv;
    *(f16x8*)&cat[lane][16] = (f16x8){0, 0, 0, 0, 0, 0, 0, 0};
    *(f16x8*)&cat[lane][24] = (f16x8){0, 0, 0, 0, 0, 0, 0, 0};

    // ---- conv1: agg1 = Adj @ X ----
    f32x4 acc1[4];
    #pragma unroll
    for (int t = 0; t < 4; t++) acc1[t] = (f32x4){0.f, 0.f, 0.f, 0.f};
    #pragma unroll
    for (int ks = 0; ks < 2; ks++) {
        f16x8 bx = *(const f16x8*)&L.XH[ln15][ks * 32 + quad * 8];
        #pragma unroll
        for (int t = 0; t < 4; t++)
            acc1[t] = __builtin_amdgcn_mfma_f32_16x16x32_f16(af[t][ks], bx, acc1[t], 0, 0, 0);
    }
    #pragma unroll
    for (int t = 0; t < 4; t++)
        #pragma unroll
        for (int r = 0; r < 4; r++)
            if (ln15 < 8) cat[t * 16 + quad * 4 + r][ln15] = (_Float16)acc1[t][r];
    WSYNC();

    // ---- lin1: h1 = relu(b1 + [agg1|x] @ Wc1) ----
    f32x4 accL[4];
    #pragma unroll
    for (int t = 0; t < 4; t++) {
        f16x8 al = *(const f16x8*)&cat[t * 16 + ln15][quad * 8];
        f32x4 ci = (f32x4){b1v, b1v, b1v, b1v};
        accL[t] = __builtin_amdgcn_mfma_f32_16x16x32_f16(al, wf1, ci, 0, 0, 0);
    }
    // write H1t (overlays Xt; clamp nodes>=54 to 0) + cat cols 16..31 (h1 root)
    #pragma unroll
    for (int t = 0; t < 4; t++) {
        f16x4 hp;
        #pragma unroll
        for (int r = 0; r < 4; r++) {
            int node = t * 16 + quad * 4 + r;
            float h = (node < NPG) ? fmaxf(accL[t][r], 0.0f) : 0.0f;
            hp[r] = (_Float16)h;
            cat[node][16 + ln15] = (_Float16)h;
        }
        *(f16x4*)&L.XH[ln15][t * 16 + quad * 4] = hp;
    }
    WSYNC();

    // ---- conv2: agg2 = Adj @ H1 (af from registers) ----
    f32x4 acc2[4];
    #pragma unroll
    for (int t = 0; t < 4; t++) acc2[t] = (f32x4){0.f, 0.f, 0.f, 0.f};
    #pragma unroll
    for (int ks = 0; ks < 2; ks++) {
        f16x8 bh = *(const f16x8*)&L.XH[ln15][ks * 32 + quad * 8];
        #pragma unroll
        for (int t = 0; t < 4; t++)
            acc2[t] = __builtin_amdgcn_mfma_f32_16x16x32_f16(af[t][ks], bh, acc2[t], 0, 0, 0);
    }
    #pragma unroll
    for (int t = 0; t < 4; t++)
        #pragma unroll
        for (int r = 0; r < 4; r++)
            cat[t * 16 + quad * 4 + r][ln15] = (_Float16)acc2[t][r];
    WSYNC();

    // ---- lin2: h2 = relu(b2 + [agg2|h1] @ Wc2); vtmp overlays XH ----
    _Float16* vt = &L.XH[0][0];
    #pragma unroll
    for (int t = 0; t < 4; t++) {
        f16x8 a2 = *(const f16x8*)&cat[t * 16 + ln15][quad * 8];
        f32x4 ci = (f32x4){b2v, b2v, b2v, b2v};
        f32x4 h2 = __builtin_amdgcn_mfma_f32_16x16x32_f16(a2, wf2, ci, 0, 0, 0);
        #pragma unroll
        for (int r = 0; r < 4; r++) {
            int node = t * 16 + quad * 4 + r;
            if (ln15 < 4 && node < NPG)
                vt[node * 4 + ln15] = (_Float16)fmaxf(h2[r], 0.0f);
        }
    }
    WSYNC();

    // ---- coalesced V write: cols 0..215 (216..255 from g_kernel) ----
    if (lane < 27)
        *(f16x8*)(v_out + (size_t)g * KPAD + lane * 8) = *(const f16x8*)&vt[lane * 8];
}

// ---------------------------------------------------------------------------
// Kernel 1b: global-feature MLP, one thread per graph. Writes V cols 216..255.
// ---------------------------------------------------------------------------
__global__ __launch_bounds__(256) void g_kernel(
    const float* __restrict__ gf,
    const float* __restrict__ Wg1, const float* __restrict__ bg1,
    const float* __restrict__ Wg2, const float* __restrict__ bg2,
    const float* __restrict__ Wg3, const float* __restrict__ bg3,
    _Float16* __restrict__ v_out)
{
    int row = blockIdx.x * 256 + threadIdx.x;
    const float* gr = gf + (size_t)row * GLOB;
    float t0[GLOB];
    #pragma unroll
    for (int i = 0; i < GLOB; i++) t0[i] = gr[i];
    float t1[8];
    #pragma unroll
    for (int j = 0; j < 8; j++) {
        float a = bg1[j];
        #pragma unroll
        for (int i = 0; i < GLOB; i++) a += t0[i] * Wg1[i * 8 + j];
        t1[j] = fmaxf(a, 0.0f);
    }
    float t2[8];
    #pragma unroll
    for (int j = 0; j < 8; j++) {
        float a = bg2[j];
        #pragma unroll
        for (int i = 0; i < 8; i++) a += t1[i] * Wg2[i * 8 + j];
        t2[j] = fmaxf(a, 0.0f);
    }
    float t3[GLOB];
    #pragma unroll
    for (int j = 0; j < GLOB; j++) {
        float a = bg3[j];
        #pragma unroll
        for (int i = 0; i < 8; i++) a += t2[i] * Wg3[i * GLOB + j];
        t3[j] = fmaxf(a, 0.0f);
    }
    _Float16* vr = v_out + (size_t)row * KPAD + 216;
    f16x8 v0 = { (_Float16)t3[0], (_Float16)t3[1], (_Float16)t3[2], (_Float16)t3[3],
                 (_Float16)t3[4], (_Float16)t3[5], (_Float16)t3[6], (_Float16)t3[7] };
    f16x8 v1 = { (_Float16)t3[8], (_Float16)t3[9], 0, 0, 0, 0, 0, 0 };
    f16x8 zz = { 0, 0, 0, 0, 0, 0, 0, 0 };
    *(f16x8*)(vr +  0) = v0;
    *(f16x8*)(vr +  8) = v1;
    *(f16x8*)(vr + 16) = zz;
    *(f16x8*)(vr + 24) = zz;
    *(f16x8*)(vr + 32) = zz;
}

// ---------------------------------------------------------------------------
// Kernel 2: out-MLP via fp16 MFMA (unchanged from round 4).
// ---------------------------------------------------------------------------
#define BTS 264

__global__ __launch_bounds__(512) void out_mlp_mfma(
    const _Float16* __restrict__ V,    // [B, KPAD] fp16
    const float* __restrict__ Wo1,     // [226, 128] fp32
    const float* __restrict__ bo1,
    const float* __restrict__ Wo2,
    const float* __restrict__ bo2,
    float* __restrict__ out)
{
    extern __shared__ _Float16 Bt[];   // [128][BTS] = 67584 B

    const int tid  = threadIdx.x;
    const int w    = tid >> 6;
    const int lane = tid & 63;
    const int ln15 = lane & 15;
    const int quad = lane >> 4;
    const int row0 = blockIdx.x * 128;

    float bo1v[8], wo2v[8];
    #pragma unroll
    for (int t = 0; t < 8; t++) {
        bo1v[t] = bo1[t * 16 + ln15];
        wo2v[t] = Wo2[t * 16 + ln15];
    }
    const float bo2v = bo2[0];

    const _Float16* Arow = V + (size_t)(row0 + w * 16 + ln15) * KPAD;
    f16x8 af[8];
    #pragma unroll
    for (int s = 0; s < 8; s++)
        af[s] = *(const f16x8*)(Arow + s * 32 + quad * 8);

    {
        int4* bz = (int4*)Bt;
        for (int i = tid; i < 4224; i += 512)
            bz[i] = make_int4(0, 0, 0, 0);
    }
    __syncthreads();
    for (int i = tid; i < 7232; i += 512) {
        int k  = i >> 5;
        int nq = (i & 31) * 4;
        float4 v = *(const float4*)(Wo1 + (size_t)k * 128 + nq);
        Bt[(nq + 0) * BTS + k] = (_Float16)v.x;
        Bt[(nq + 1) * BTS + k] = (_Float16)v.y;
        Bt[(nq + 2) * BTS + k] = (_Float16)v.z;
        Bt[(nq + 3) * BTS + k] = (_Float16)v.w;
    }
    __syncthreads();

    f32x4 acc[8];
    #pragma unroll
    for (int t = 0; t < 8; t++) acc[t] = (f32x4){0.f, 0.f, 0.f, 0.f};

    for (int s = 0; s < 8; s++) {
        #pragma unroll
        for (int t = 0; t < 8; t++) {
            f16x8 bf = *(const f16x8*)&Bt[(t * 16 + ln15) * BTS + s * 32 + quad * 8];
            acc[t] = __builtin_amdgcn_mfma_f32_16x16x32_f16(af[s], bf, acc[t], 0, 0, 0);
        }
    }

    #pragma unroll
    for (int rr = 0; rr < 4; rr++) {
        float p = 0.0f;
        #pragma unroll
        for (int t = 0; t < 8; t++) {
            float h = fmaxf(acc[t][rr] + bo1v[t], 0.0f);
            p += h * wo2v[t];
        }
        p += __shfl_xor(p, 1);
        p += __shfl_xor(p, 2);
        p += __shfl_xor(p, 4);
        p += __shfl_xor(p, 8);
        if (ln15 == rr) {
            int row = row0 + w * 16 + quad * 4 + rr;
            out[row] = 1.0f / (1.0f + expf(-(p + bo2v)));
        }
    }
}

// ---------------------------------------------------------------------------
extern "C" void kernel_launch(void* const* d_in, const int* in_sizes, int n_in,
                              void* d_out, int out_size, void* d_ws, size_t ws_size,
                              hipStream_t stream) {
    const float* x        = (const float*)d_in[0];
    const int*   ei       = (const int*)  d_in[1];
    const float* ea       = (const float*)d_in[2];
    const float* gf       = (const float*)d_in[3];
    const float* W_rel1   = (const float*)d_in[4];
    const float* b1       = (const float*)d_in[5];
    const float* W_root1  = (const float*)d_in[6];
    const float* W_rel2   = (const float*)d_in[7];
    const float* b2       = (const float*)d_in[8];
    const float* W_root2  = (const float*)d_in[9];
    const float* Wg1      = (const float*)d_in[10];
    const float* bg1      = (const float*)d_in[11];
    const float* Wg2      = (const float*)d_in[12];
    const float* bg2      = (const float*)d_in[13];
    const float* Wg3      = (const float*)d_in[14];
    const float* bg3      = (const float*)d_in[15];
    const float* Wo1      = (const float*)d_in[16];
    const float* bo1      = (const float*)d_in[17];
    const float* Wo2      = (const float*)d_in[18];
    const float* bo2      = (const float*)d_in[19];

    float* out   = (float*)d_out;
    _Float16* V  = (_Float16*)d_ws;             // [B, KPAD] fp16

    const int B = out_size;                     // 32768
    const int E = in_sizes[1] / 2;

    graph_kernel<<<B / GPB, 128, 0, stream>>>(
        x, ei, ea,
        W_rel1, b1, W_root1, W_rel2, b2, W_root2,
        V, E);

    g_kernel<<<B / 256, 256, 0, stream>>>(gf, Wg1, bg1, Wg2, bg2, Wg3, bg3, V);

    out_mlp_mfma<<<B / 128, 512, 128 * BTS * sizeof(_Float16), stream>>>(
        V, Wo1, bo1, Wo2, bo2, out);
}

// Round 6
// 229.201 us; speedup vs baseline: 3.6488x; 1.1102x over previous
//
#include <hip/hip_runtime.h>
#include <hip/hip_fp16.h>
#include <math.h>

#define NPG 54
#define EPG 144
#define GLOB 10
#define KPAD 256   // V row: 216 embeds + 10 global + 30 zero pad (fp16)
#define GPB 2      // graphs (waves) per block in graph_kernel

typedef _Float16 f16x8 __attribute__((ext_vector_type(8)));
typedef _Float16 f16x4 __attribute__((ext_vector_type(4)));
typedef float    f32x4 __attribute__((ext_vector_type(4)));

// intra-wave LDS fence: all this wave's DS ops complete + compiler ordering.
// (waves in a block share no LDS region -> no s_barrier needed anywhere)
#define WSYNC() asm volatile("s_waitcnt lgkmcnt(0)" ::: "memory")

// ---------------------------------------------------------------------------
// Kernel 1: one WAVE per graph, 2 graphs per 128-thread block, NO barriers.
// Adjacency built directly with native packed-fp16 LDS atomics
// (ds_pk_add_f16 via unsafeAtomicAdd) -- no CSR, no dedupe loop.
// LDS per graph = 11520 B (23 KB/block -> 7 blocks/CU = 14 waves):
//   Adj[64][72] fp16 (9216 B); cat[64][40] overlays it after A-frags -> regs
//   XH[16][72] fp16 (2304 B): Xt -> H1t -> vtmp (phase-disjoint)
// Weights live in registers (B-fragment layout), staged via global loads.
// ---------------------------------------------------------------------------
struct __align__(16) GL {
    _Float16 Adj[64][72];   // 9216 B
    _Float16 XH[16][72];    // 2304 B
};

__global__ __launch_bounds__(128, 4) void graph_kernel(
    const float* __restrict__ x,
    const int*   __restrict__ edge_index,
    const float* __restrict__ edge_attr,
    const float* __restrict__ W_rel1, const float* __restrict__ b1,
    const float* __restrict__ W_root1,
    const float* __restrict__ W_rel2, const float* __restrict__ b2,
    const float* __restrict__ W_root2,
    _Float16* __restrict__ v_out,     // [B, KPAD] fp16
    int E_total)
{
    __shared__ GL S[GPB];
    const int tid  = threadIdx.x;
    const int w    = tid >> 6;
    const int lane = tid & 63;
    const int ln15 = lane & 15;
    const int quad = lane >> 4;
    const int g    = blockIdx.x * GPB + w;
    GL& L = S[w];
    const int nbase = g * NPG;
    const int ebase = g * EPG;

    _Float16 (*cat)[40] = (_Float16(*)[40])&L.Adj[0][0];       // overlay

    // ---- issue global loads FIRST (stay in flight through zeroing) ----
    int   esrc_r[3], edst_r[3];
    float ea_r[3];
    #pragma unroll
    for (int k = 0; k < 3; k++) {
        int e = lane + 64 * k;
        if (e < EPG) {
            esrc_r[k] = edge_index[ebase + e] - nbase;
            edst_r[k] = edge_index[(size_t)E_total + ebase + e] - nbase;
            ea_r[k]   = edge_attr[ebase + e];
        } else { esrc_r[k] = 0; edst_r[k] = -1; ea_r[k] = 0.0f; }
    }
    f16x8 xv = {0, 0, 0, 0, 0, 0, 0, 0};
    if (lane < NPG) {
        const float4* xg4 = (const float4*)(x + (size_t)(nbase + lane) * 8);
        float4 lo = xg4[0], hi = xg4[1];
        xv = (f16x8){ (_Float16)lo.x, (_Float16)lo.y, (_Float16)lo.z, (_Float16)lo.w,
                      (_Float16)hi.x, (_Float16)hi.y, (_Float16)hi.z, (_Float16)hi.w };
    }

    // ---- weight B-fragments in registers ----
    // Wc1[k][n]: k<8 Wrel1[k][n], k<16 Wroot1[k-8][n], else 0.  n=ln15, k=quad*8+j
    f16x8 wf1 = {0, 0, 0, 0, 0, 0, 0, 0};
    if (quad == 0) {
        #pragma unroll
        for (int j = 0; j < 8; j++) wf1[j] = (_Float16)W_rel1[j * 16 + ln15];
    } else if (quad == 1) {
        #pragma unroll
        for (int j = 0; j < 8; j++) wf1[j] = (_Float16)W_root1[j * 16 + ln15];
    }
    // Wc2[k][n]: n<4: k<16 Wrel2[k][n], k<32 Wroot2[k-16][n]; n>=4: 0
    f16x8 wf2 = {0, 0, 0, 0, 0, 0, 0, 0};
    if (ln15 < 4) {
        #pragma unroll
        for (int j = 0; j < 8; j++) {
            int k = quad * 8 + j;
            wf2[j] = (_Float16)((k < 16) ? W_rel2[k * 4 + ln15]
                                         : W_root2[(k - 16) * 4 + ln15]);
        }
    }
    const float b1v = b1[ln15];
    const float b2v = b2[ln15 & 3];

    // ---- zero the whole per-graph region (Adj + XH = 720 uint4) ----
    {
        uint4* z = (uint4*)&L;
        #pragma unroll
        for (int i = lane; i < 720; i += 64) z[i] = make_uint4(0, 0, 0, 0);
    }
    // stage Xt[feat][node] (B operand for conv1)
    if (lane < NPG) {
        #pragma unroll
        for (int f = 0; f < 8; f++) L.XH[f][lane] = xv[f];
    }
    WSYNC();   // zeros + Xt in LDS before atomics land

    // ---- build Adj directly: one ds_pk_add_f16 per edge (dups sum in HW) ----
    #pragma unroll
    for (int k = 0; k < 3; k++) {
        if (edst_r[k] >= 0) {
            int s = esrc_r[k];
            __half2* cell = (__half2*)&L.Adj[edst_r[k]][s & ~1];
            __half a16 = __float2half(ea_r[k]);
            __half z16 = __float2half(0.0f);
            __half2 val = (s & 1) ? __halves2half2(z16, a16)
                                  : __halves2half2(a16, z16);
            unsafeAtomicAdd(cell, val);
        }
    }
    WSYNC();

    // ---- A-fragments (Adj) -> registers; Adj LDS becomes dead ----
    f16x8 af[4][2];
    #pragma unroll
    for (int t = 0; t < 4; t++)
        #pragma unroll
        for (int ks = 0; ks < 2; ks++)
            af[t][ks] = *(const f16x8*)&L.Adj[t * 16 + ln15][ks * 32 + quad * 8];
    WSYNC();   // af in regs before cat overlay writes

    // ---- cat overlay: x-root (cols 8..15 from regs) + zeros (cols 16..31) ----
    if (lane < NPG) *(f16x8*)&cat[lane][8] = xv;
    *(f16x8*)&cat[lane][16] = (f16x8){0, 0, 0, 0, 0, 0, 0, 0};
    *(f16x8*)&cat[lane][24] = (f16x8){0, 0, 0, 0, 0, 0, 0, 0};

    // ---- conv1: agg1 = Adj @ X ----
    f32x4 acc1[4];
    #pragma unroll
    for (int t = 0; t < 4; t++) acc1[t] = (f32x4){0.f, 0.f, 0.f, 0.f};
    #pragma unroll
    for (int ks = 0; ks < 2; ks++) {
        f16x8 bx = *(const f16x8*)&L.XH[ln15][ks * 32 + quad * 8];
        #pragma unroll
        for (int t = 0; t < 4; t++)
            acc1[t] = __builtin_amdgcn_mfma_f32_16x16x32_f16(af[t][ks], bx, acc1[t], 0, 0, 0);
    }
    #pragma unroll
    for (int t = 0; t < 4; t++)
        #pragma unroll
        for (int r = 0; r < 4; r++)
            if (ln15 < 8) cat[t * 16 + quad * 4 + r][ln15] = (_Float16)acc1[t][r];
    WSYNC();

    // ---- lin1: h1 = relu(b1 + [agg1|x] @ Wc1) ----
    f32x4 accL[4];
    #pragma unroll
    for (int t = 0; t < 4; t++) {
        f16x8 al = *(const f16x8*)&cat[t * 16 + ln15][quad * 8];
        f32x4 ci = (f32x4){b1v, b1v, b1v, b1v};
        accL[t] = __builtin_amdgcn_mfma_f32_16x16x32_f16(al, wf1, ci, 0, 0, 0);
    }
    // write H1t (overlays Xt; clamp nodes>=54 to 0) + cat cols 16..31 (h1 root)
    #pragma unroll
    for (int t = 0; t < 4; t++) {
        f16x4 hp;
        #pragma unroll
        for (int r = 0; r < 4; r++) {
            int node = t * 16 + quad * 4 + r;
            float h = (node < NPG) ? fmaxf(accL[t][r], 0.0f) : 0.0f;
            hp[r] = (_Float16)h;
            cat[node][16 + ln15] = (_Float16)h;
        }
        *(f16x4*)&L.XH[ln15][t * 16 + quad * 4] = hp;
    }
    WSYNC();

    // ---- conv2: agg2 = Adj @ H1 (af from registers) ----
    f32x4 acc2[4];
    #pragma unroll
    for (int t = 0; t < 4; t++) acc2[t] = (f32x4){0.f, 0.f, 0.f, 0.f};
    #pragma unroll
    for (int ks = 0; ks < 2; ks++) {
        f16x8 bh = *(const f16x8*)&L.XH[ln15][ks * 32 + quad * 8];
        #pragma unroll
        for (int t = 0; t < 4; t++)
            acc2[t] = __builtin_amdgcn_mfma_f32_16x16x32_f16(af[t][ks], bh, acc2[t], 0, 0, 0);
    }
    #pragma unroll
    for (int t = 0; t < 4; t++)
        #pragma unroll
        for (int r = 0; r < 4; r++)
            cat[t * 16 + quad * 4 + r][ln15] = (_Float16)acc2[t][r];
    WSYNC();

    // ---- lin2: h2 = relu(b2 + [agg2|h1] @ Wc2); vtmp overlays XH ----
    _Float16* vt = &L.XH[0][0];
    #pragma unroll
    for (int t = 0; t < 4; t++) {
        f16x8 a2 = *(const f16x8*)&cat[t * 16 + ln15][quad * 8];
        f32x4 ci = (f32x4){b2v, b2v, b2v, b2v};
        f32x4 h2 = __builtin_amdgcn_mfma_f32_16x16x32_f16(a2, wf2, ci, 0, 0, 0);
        #pragma unroll
        for (int r = 0; r < 4; r++) {
            int node = t * 16 + quad * 4 + r;
            if (ln15 < 4 && node < NPG)
                vt[node * 4 + ln15] = (_Float16)fmaxf(h2[r], 0.0f);
        }
    }
    WSYNC();

    // ---- coalesced V write: cols 0..215 (216..255 from g_kernel) ----
    if (lane < 27)
        *(f16x8*)(v_out + (size_t)g * KPAD + lane * 8) = *(const f16x8*)&vt[lane * 8];
}

// ---------------------------------------------------------------------------
// Kernel 1b: global-feature MLP, one thread per graph. Writes V cols 216..255.
// ---------------------------------------------------------------------------
__global__ __launch_bounds__(256) void g_kernel(
    const float* __restrict__ gf,
    const float* __restrict__ Wg1, const float* __restrict__ bg1,
    const float* __restrict__ Wg2, const float* __restrict__ bg2,
    const float* __restrict__ Wg3, const float* __restrict__ bg3,
    _Float16* __restrict__ v_out)
{
    int row = blockIdx.x * 256 + threadIdx.x;
    const float* gr = gf + (size_t)row * GLOB;
    float t0[GLOB];
    #pragma unroll
    for (int i = 0; i < GLOB; i++) t0[i] = gr[i];
    float t1[8];
    #pragma unroll
    for (int j = 0; j < 8; j++) {
        float a = bg1[j];
        #pragma unroll
        for (int i = 0; i < GLOB; i++) a += t0[i] * Wg1[i * 8 + j];
        t1[j] = fmaxf(a, 0.0f);
    }
    float t2[8];
    #pragma unroll
    for (int j = 0; j < 8; j++) {
        float a = bg2[j];
        #pragma unroll
        for (int i = 0; i < 8; i++) a += t1[i] * Wg2[i * 8 + j];
        t2[j] = fmaxf(a, 0.0f);
    }
    float t3[GLOB];
    #pragma unroll
    for (int j = 0; j < GLOB; j++) {
        float a = bg3[j];
        #pragma unroll
        for (int i = 0; i < 8; i++) a += t2[i] * Wg3[i * GLOB + j];
        t3[j] = fmaxf(a, 0.0f);
    }
    _Float16* vr = v_out + (size_t)row * KPAD + 216;
    f16x8 v0 = { (_Float16)t3[0], (_Float16)t3[1], (_Float16)t3[2], (_Float16)t3[3],
                 (_Float16)t3[4], (_Float16)t3[5], (_Float16)t3[6], (_Float16)t3[7] };
    f16x8 v1 = { (_Float16)t3[8], (_Float16)t3[9], 0, 0, 0, 0, 0, 0 };
    f16x8 zz = { 0, 0, 0, 0, 0, 0, 0, 0 };
    *(f16x8*)(vr +  0) = v0;
    *(f16x8*)(vr +  8) = v1;
    *(f16x8*)(vr + 16) = zz;
    *(f16x8*)(vr + 24) = zz;
    *(f16x8*)(vr + 32) = zz;
}

// ---------------------------------------------------------------------------
// Kernel 2: out-MLP via fp16 MFMA (unchanged).
// ---------------------------------------------------------------------------
#define BTS 264

__global__ __launch_bounds__(512) void out_mlp_mfma(
    const _Float16* __restrict__ V,    // [B, KPAD] fp16
    const float* __restrict__ Wo1,     // [226, 128] fp32
    const float* __restrict__ bo1,
    const float* __restrict__ Wo2,
    const float* __restrict__ bo2,
    float* __restrict__ out)
{
    extern __shared__ _Float16 Bt[];   // [128][BTS] = 67584 B

    const int tid  = threadIdx.x;
    const int w    = tid >> 6;
    const int lane = tid & 63;
    const int ln15 = lane & 15;
    const int quad = lane >> 4;
    const int row0 = blockIdx.x * 128;

    float bo1v[8], wo2v[8];
    #pragma unroll
    for (int t = 0; t < 8; t++) {
        bo1v[t] = bo1[t * 16 + ln15];
        wo2v[t] = Wo2[t * 16 + ln15];
    }
    const float bo2v = bo2[0];

    const _Float16* Arow = V + (size_t)(row0 + w * 16 + ln15) * KPAD;
    f16x8 af[8];
    #pragma unroll
    for (int s = 0; s < 8; s++)
        af[s] = *(const f16x8*)(Arow + s * 32 + quad * 8);

    {
        int4* bz = (int4*)Bt;
        for (int i = tid; i < 4224; i += 512)
            bz[i] = make_int4(0, 0, 0, 0);
    }
    __syncthreads();
    for (int i = tid; i < 7232; i += 512) {
        int k  = i >> 5;
        int nq = (i & 31) * 4;
        float4 v = *(const float4*)(Wo1 + (size_t)k * 128 + nq);
        Bt[(nq + 0) * BTS + k] = (_Float16)v.x;
        Bt[(nq + 1) * BTS + k] = (_Float16)v.y;
        Bt[(nq + 2) * BTS + k] = (_Float16)v.z;
        Bt[(nq + 3) * BTS + k] = (_Float16)v.w;
    }
    __syncthreads();

    f32x4 acc[8];
    #pragma unroll
    for (int t = 0; t < 8; t++) acc[t] = (f32x4){0.f, 0.f, 0.f, 0.f};

    for (int s = 0; s < 8; s++) {
        #pragma unroll
        for (int t = 0; t < 8; t++) {
            f16x8 bf = *(const f16x8*)&Bt[(t * 16 + ln15) * BTS + s * 32 + quad * 8];
            acc[t] = __builtin_amdgcn_mfma_f32_16x16x32_f16(af[s], bf, acc[t], 0, 0, 0);
        }
    }

    #pragma unroll
    for (int rr = 0; rr < 4; rr++) {
        float p = 0.0f;
        #pragma unroll
        for (int t = 0; t < 8; t++) {
            float h = fmaxf(acc[t][rr] + bo1v[t], 0.0f);
            p += h * wo2v[t];
        }
        p += __shfl_xor(p, 1);
        p += __shfl_xor(p, 2);
        p += __shfl_xor(p, 4);
        p += __shfl_xor(p, 8);
        if (ln15 == rr) {
            int row = row0 + w * 16 + quad * 4 + rr;
            out[row] = 1.0f / (1.0f + expf(-(p + bo2v)));
        }
    }
}

// ---------------------------------------------------------------------------
extern "C" void kernel_launch(void* const* d_in, const int* in_sizes, int n_in,
                              void* d_out, int out_size, void* d_ws, size_t ws_size,
                              hipStream_t stream) {
    const float* x        = (const float*)d_in[0];
    const int*   ei       = (const int*)  d_in[1];
    const float* ea       = (const float*)d_in[2];
    const float* gf       = (const float*)d_in[3];
    const float* W_rel1   = (const float*)d_in[4];
    const float* b1       = (const float*)d_in[5];
    const float* W_root1  = (const float*)d_in[6];
    const float* W_rel2   = (const float*)d_in[7];
    const float* b2       = (const float*)d_in[8];
    const float* W_root2  = (const float*)d_in[9];
    const float* Wg1      = (const float*)d_in[10];
    const float* bg1      = (const float*)d_in[11];
    const float* Wg2      = (const float*)d_in[12];
    const float* bg2      = (const float*)d_in[13];
    const float* Wg3      = (const float*)d_in[14];
    const float* bg3      = (const float*)d_in[15];
    const float* Wo1      = (const float*)d_in[16];
    const float* bo1      = (const float*)d_in[17];
    const float* Wo2      = (const float*)d_in[18];
    const float* bo2      = (const float*)d_in[19];

    float* out   = (float*)d_out;
    _Float16* V  = (_Float16*)d_ws;             // [B, KPAD] fp16

    const int B = out_size;                     // 32768
    const int E = in_sizes[1] / 2;

    graph_kernel<<<B / GPB, 128, 0, stream>>>(
        x, ei, ea,
        W_rel1, b1, W_root1, W_rel2, b2, W_root2,
        V, E);

    g_kernel<<<B / 256, 256, 0, stream>>>(gf, Wg1, bg1, Wg2, bg2, Wg3, bg3, V);

    out_mlp_mfma<<<B / 128, 512, 128 * BTS * sizeof(_Float16), stream>>>(
        V, Wo1, bo1, Wo2, bo2, out);
}

// Round 7
// 219.735 us; speedup vs baseline: 3.8060x; 1.0431x over previous
//
#include <hip/hip_runtime.h>
#include <hip/hip_fp16.h>
#include <math.h>

#define NPG 54
#define EPG 144
#define GLOB 10
#define VROW 216   // V row: 216 embeds only (g fused into out_mlp)
#define GPB 2      // graphs (waves) per block in graph_kernel

typedef _Float16 f16x8 __attribute__((ext_vector_type(8)));
typedef _Float16 f16x4 __attribute__((ext_vector_type(4)));
typedef float    f32x4 __attribute__((ext_vector_type(4)));

// intra-wave LDS fence: all this wave's DS ops complete + compiler ordering.
// (waves in a block share no LDS region -> no s_barrier needed anywhere)
#define WSYNC() asm volatile("s_waitcnt lgkmcnt(0)" ::: "memory")

// ---------------------------------------------------------------------------
// Kernel 1: one WAVE per graph, 2 graphs per 128-thread block, NO barriers.
// Adjacency built with native packed-fp16 LDS atomics (ds_pk_add_f16).
// LDS per graph = 10080 B (20160/block -> 8 blocks/CU = 16 waves):
//   Adj[54][72] fp16 (7776 B); fragment reads of "rows 54..63" alias into
//     the zeroed/finite XH region -- those D rows are clamped downstream.
//   cat[64][40] overlays Adj once A-frags are in registers.
//   XH[16][72] (2304 B): Xt -> H1t -> vtmp (phase-disjoint).
// Weights live in registers (B-fragment layout), staged via global loads.
// ---------------------------------------------------------------------------
struct __align__(16) GL {
    _Float16 Adj[NPG][72];  // 7776 B
    _Float16 XH[16][72];    // 2304 B
};

__global__ __launch_bounds__(128, 4) void graph_kernel(
    const float* __restrict__ x,
    const int*   __restrict__ edge_index,
    const float* __restrict__ edge_attr,
    const float* __restrict__ W_rel1, const float* __restrict__ b1,
    const float* __restrict__ W_root1,
    const float* __restrict__ W_rel2, const float* __restrict__ b2,
    const float* __restrict__ W_root2,
    _Float16* __restrict__ v_out,     // [B, VROW] fp16
    int E_total)
{
    __shared__ GL S[GPB];
    const int tid  = threadIdx.x;
    const int w    = tid >> 6;
    const int lane = tid & 63;
    const int ln15 = lane & 15;
    const int quad = lane >> 4;
    const int g    = blockIdx.x * GPB + w;
    GL& L = S[w];
    const int nbase = g * NPG;
    const int ebase = g * EPG;

    _Float16 (*cat)[40] = (_Float16(*)[40])&L.Adj[0][0];       // overlay

    // ---- issue global loads FIRST (stay in flight through zeroing) ----
    int   esrc_r[3], edst_r[3];
    float ea_r[3];
    #pragma unroll
    for (int k = 0; k < 3; k++) {
        int e = lane + 64 * k;
        if (e < EPG) {
            esrc_r[k] = edge_index[ebase + e] - nbase;
            edst_r[k] = edge_index[(size_t)E_total + ebase + e] - nbase;
            ea_r[k]   = edge_attr[ebase + e];
        } else { esrc_r[k] = 0; edst_r[k] = -1; ea_r[k] = 0.0f; }
    }
    f16x8 xv = {0, 0, 0, 0, 0, 0, 0, 0};
    if (lane < NPG) {
        const float4* xg4 = (const float4*)(x + (size_t)(nbase + lane) * 8);
        float4 lo = xg4[0], hi = xg4[1];
        xv = (f16x8){ (_Float16)lo.x, (_Float16)lo.y, (_Float16)lo.z, (_Float16)lo.w,
                      (_Float16)hi.x, (_Float16)hi.y, (_Float16)hi.z, (_Float16)hi.w };
    }

    // ---- weight B-fragments in registers ----
    // Wc1[k][n]: k<8 Wrel1[k][n], k<16 Wroot1[k-8][n], else 0.  n=ln15, k=quad*8+j
    f16x8 wf1 = {0, 0, 0, 0, 0, 0, 0, 0};
    if (quad == 0) {
        #pragma unroll
        for (int j = 0; j < 8; j++) wf1[j] = (_Float16)W_rel1[j * 16 + ln15];
    } else if (quad == 1) {
        #pragma unroll
        for (int j = 0; j < 8; j++) wf1[j] = (_Float16)W_root1[j * 16 + ln15];
    }
    // Wc2[k][n]: n<4: k<16 Wrel2[k][n], k<32 Wroot2[k-16][n]; n>=4: 0
    f16x8 wf2 = {0, 0, 0, 0, 0, 0, 0, 0};
    if (ln15 < 4) {
        #pragma unroll
        for (int j = 0; j < 8; j++) {
            int k = quad * 8 + j;
            wf2[j] = (_Float16)((k < 16) ? W_rel2[k * 4 + ln15]
                                         : W_root2[(k - 16) * 4 + ln15]);
        }
    }
    const float b1v = b1[ln15];
    const float b2v = b2[ln15 & 3];

    // ---- zero the whole per-graph region (Adj54 + XH = 630 uint4) ----
    {
        uint4* z = (uint4*)&L;
        #pragma unroll
        for (int i = lane; i < 630; i += 64) z[i] = make_uint4(0, 0, 0, 0);
    }
    // stage Xt[feat][node] (B operand for conv1)
    if (lane < NPG) {
        #pragma unroll
        for (int f = 0; f < 8; f++) L.XH[f][lane] = xv[f];
    }
    WSYNC();   // zeros + Xt in LDS before atomics land

    // ---- build Adj directly: one ds_pk_add_f16 per edge (dups sum in HW) ----
    #pragma unroll
    for (int k = 0; k < 3; k++) {
        if (edst_r[k] >= 0) {
            int s = esrc_r[k];
            __half2* cell = (__half2*)&L.Adj[edst_r[k]][s & ~1];
            __half a16 = __float2half(ea_r[k]);
            __half z16 = __float2half(0.0f);
            __half2 val = (s & 1) ? __halves2half2(z16, a16)
                                  : __halves2half2(a16, z16);
            unsafeAtomicAdd(cell, val);
        }
    }
    WSYNC();

    // ---- A-fragments (Adj) -> registers; rows 54..63 read finite garbage
    //      from the XH region (in-bounds), clamped downstream ----
    f16x8 af[4][2];
    #pragma unroll
    for (int t = 0; t < 4; t++)
        #pragma unroll
        for (int ks = 0; ks < 2; ks++)
            af[t][ks] = *(const f16x8*)&L.Adj[t * 16 + ln15][ks * 32 + quad * 8];
    WSYNC();   // af in regs before cat overlay writes

    // ---- cat overlay: x-root (cols 8..15). cols 16..31 are stale-but-finite
    //      (zeroed at start); wf1 is 0 there so no zero-fill needed. ----
    if (lane < NPG) *(f16x8*)&cat[lane][8] = xv;

    // ---- conv1: agg1 = Adj @ X ----
    f32x4 acc1[4];
    #pragma unroll
    for (int t = 0; t < 4; t++) acc1[t] = (f32x4){0.f, 0.f, 0.f, 0.f};
    #pragma unroll
    for (int ks = 0; ks < 2; ks++) {
        f16x8 bx = *(const f16x8*)&L.XH[ln15][ks * 32 + quad * 8];
        #pragma unroll
        for (int t = 0; t < 4; t++)
            acc1[t] = __builtin_amdgcn_mfma_f32_16x16x32_f16(af[t][ks], bx, acc1[t], 0, 0, 0);
    }
    #pragma unroll
    for (int t = 0; t < 4; t++)
        #pragma unroll
        for (int r = 0; r < 4; r++)
            if (ln15 < 8) cat[t * 16 + quad * 4 + r][ln15] = (_Float16)acc1[t][r];
    WSYNC();

    // ---- lin1: h1 = relu(b1 + [agg1|x] @ Wc1) ----
    f32x4 accL[4];
    #pragma unroll
    for (int t = 0; t < 4; t++) {
        f16x8 al = *(const f16x8*)&cat[t * 16 + ln15][quad * 8];
        f32x4 ci = (f32x4){b1v, b1v, b1v, b1v};
        accL[t] = __builtin_amdgcn_mfma_f32_16x16x32_f16(al, wf1, ci, 0, 0, 0);
    }
    // write H1t (overlays Xt; clamp nodes>=54 to 0) + cat cols 16..31 (h1 root)
    #pragma unroll
    for (int t = 0; t < 4; t++) {
        f16x4 hp;
        #pragma unroll
        for (int r = 0; r < 4; r++) {
            int node = t * 16 + quad * 4 + r;
            float h = (node < NPG) ? fmaxf(accL[t][r], 0.0f) : 0.0f;
            hp[r] = (_Float16)h;
            cat[node][16 + ln15] = (_Float16)h;
        }
        *(f16x4*)&L.XH[ln15][t * 16 + quad * 4] = hp;
    }
    WSYNC();

    // ---- conv2: agg2 = Adj @ H1 (af from registers) ----
    f32x4 acc2[4];
    #pragma unroll
    for (int t = 0; t < 4; t++) acc2[t] = (f32x4){0.f, 0.f, 0.f, 0.f};
    #pragma unroll
    for (int ks = 0; ks < 2; ks++) {
        f16x8 bh = *(const f16x8*)&L.XH[ln15][ks * 32 + quad * 8];
        #pragma unroll
        for (int t = 0; t < 4; t++)
            acc2[t] = __builtin_amdgcn_mfma_f32_16x16x32_f16(af[t][ks], bh, acc2[t], 0, 0, 0);
    }
    #pragma unroll
    for (int t = 0; t < 4; t++)
        #pragma unroll
        for (int r = 0; r < 4; r++)
            cat[t * 16 + quad * 4 + r][ln15] = (_Float16)acc2[t][r];
    WSYNC();

    // ---- lin2: h2 = relu(b2 + [agg2|h1] @ Wc2); vtmp overlays XH ----
    _Float16* vt = &L.XH[0][0];
    #pragma unroll
    for (int t = 0; t < 4; t++) {
        f16x8 a2 = *(const f16x8*)&cat[t * 16 + ln15][quad * 8];
        f32x4 ci = (f32x4){b2v, b2v, b2v, b2v};
        f32x4 h2 = __builtin_amdgcn_mfma_f32_16x16x32_f16(a2, wf2, ci, 0, 0, 0);
        #pragma unroll
        for (int r = 0; r < 4; r++) {
            int node = t * 16 + quad * 4 + r;
            if (ln15 < 4 && node < NPG)
                vt[node * 4 + ln15] = (_Float16)fmaxf(h2[r], 0.0f);
        }
    }
    WSYNC();

    // ---- coalesced V write: cols 0..215 ----
    if (lane < 27)
        *(f16x8*)(v_out + (size_t)g * VROW + lane * 8) = *(const f16x8*)&vt[lane * 8];
}

// ---------------------------------------------------------------------------
// Kernel 2: out-MLP via fp16 MFMA, with the 10->8->8->10 global MLP fused
// (each lane computes its own row's g in fp32; cols 216..225 of the concat
// enter as register A-fragments, cols 226..255 are zeros).
// ---------------------------------------------------------------------------
#define BTS 264

__global__ __launch_bounds__(512) void out_mlp_mfma(
    const _Float16* __restrict__ V,    // [B, VROW] fp16
    const float* __restrict__ gf,      // [B, 10]
    const float* __restrict__ Wg1, const float* __restrict__ bg1,
    const float* __restrict__ Wg2, const float* __restrict__ bg2,
    const float* __restrict__ Wg3, const float* __restrict__ bg3,
    const float* __restrict__ Wo1,     // [226, 128] fp32
    const float* __restrict__ bo1,
    const float* __restrict__ Wo2,
    const float* __restrict__ bo2,
    float* __restrict__ out)
{
    extern __shared__ _Float16 Bt[];   // [128][BTS] = 67584 B

    const int tid  = threadIdx.x;
    const int w    = tid >> 6;
    const int lane = tid & 63;
    const int ln15 = lane & 15;
    const int quad = lane >> 4;
    const int row0 = blockIdx.x * 128;
    const int row  = row0 + w * 16 + ln15;

    float bo1v[8], wo2v[8];
    #pragma unroll
    for (int t = 0; t < 8; t++) {
        bo1v[t] = bo1[t * 16 + ln15];
        wo2v[t] = Wo2[t * 16 + ln15];
    }
    const float bo2v = bo2[0];

    // ---- per-lane global-MLP for this lane's row (fp32) ----
    float t3[GLOB];
    {
        const float* gr = gf + (size_t)row * GLOB;
        float t0[GLOB];
        #pragma unroll
        for (int i = 0; i < GLOB; i++) t0[i] = gr[i];
        float t1[8];
        #pragma unroll
        for (int j = 0; j < 8; j++) {
            float a = bg1[j];
            #pragma unroll
            for (int i = 0; i < GLOB; i++) a += t0[i] * Wg1[i * 8 + j];
            t1[j] = fmaxf(a, 0.0f);
        }
        float t2[8];
        #pragma unroll
        for (int j = 0; j < 8; j++) {
            float a = bg2[j];
            #pragma unroll
            for (int i = 0; i < 8; i++) a += t1[i] * Wg2[i * 8 + j];
            t2[j] = fmaxf(a, 0.0f);
        }
        #pragma unroll
        for (int j = 0; j < GLOB; j++) {
            float a = bg3[j];
            #pragma unroll
            for (int i = 0; i < 8; i++) a += t2[i] * Wg3[i * GLOB + j];
            t3[j] = fmaxf(a, 0.0f);
        }
    }

    // ---- A-fragments: s<6 from V; s=6 quad3 + s=7 quad0 from g ----
    const _Float16* Arow = V + (size_t)row * VROW;
    f16x8 af[8];
    #pragma unroll
    for (int s = 0; s < 6; s++)
        af[s] = *(const f16x8*)(Arow + s * 32 + quad * 8);
    if (quad == 3)
        af[6] = (f16x8){ (_Float16)t3[0], (_Float16)t3[1], (_Float16)t3[2], (_Float16)t3[3],
                         (_Float16)t3[4], (_Float16)t3[5], (_Float16)t3[6], (_Float16)t3[7] };
    else
        af[6] = *(const f16x8*)(Arow + 192 + quad * 8);
    af[7] = (f16x8){0, 0, 0, 0, 0, 0, 0, 0};
    if (quad == 0) { af[7][0] = (_Float16)t3[8]; af[7][1] = (_Float16)t3[9]; }

    // ---- zero Bt, then stage Wo1 transposed fp16 ----
    {
        int4* bz = (int4*)Bt;
        for (int i = tid; i < 4224; i += 512)
            bz[i] = make_int4(0, 0, 0, 0);
    }
    __syncthreads();
    for (int i = tid; i < 7232; i += 512) {
        int k  = i >> 5;
        int nq = (i & 31) * 4;
        float4 v = *(const float4*)(Wo1 + (size_t)k * 128 + nq);
        Bt[(nq + 0) * BTS + k] = (_Float16)v.x;
        Bt[(nq + 1) * BTS + k] = (_Float16)v.y;
        Bt[(nq + 2) * BTS + k] = (_Float16)v.z;
        Bt[(nq + 3) * BTS + k] = (_Float16)v.w;
    }
    __syncthreads();

    f32x4 acc[8];
    #pragma unroll
    for (int t = 0; t < 8; t++) acc[t] = (f32x4){0.f, 0.f, 0.f, 0.f};

    for (int s = 0; s < 8; s++) {
        #pragma unroll
        for (int t = 0; t < 8; t++) {
            f16x8 bf = *(const f16x8*)&Bt[(t * 16 + ln15) * BTS + s * 32 + quad * 8];
            acc[t] = __builtin_amdgcn_mfma_f32_16x16x32_f16(af[s], bf, acc[t], 0, 0, 0);
        }
    }

    #pragma unroll
    for (int rr = 0; rr < 4; rr++) {
        float p = 0.0f;
        #pragma unroll
        for (int t = 0; t < 8; t++) {
            float h = fmaxf(acc[t][rr] + bo1v[t], 0.0f);
            p += h * wo2v[t];
        }
        p += __shfl_xor(p, 1);
        p += __shfl_xor(p, 2);
        p += __shfl_xor(p, 4);
        p += __shfl_xor(p, 8);
        if (ln15 == rr) {
            int orow = row0 + w * 16 + quad * 4 + rr;
            out[orow] = 1.0f / (1.0f + expf(-(p + bo2v)));
        }
    }
}

// ---------------------------------------------------------------------------
extern "C" void kernel_launch(void* const* d_in, const int* in_sizes, int n_in,
                              void* d_out, int out_size, void* d_ws, size_t ws_size,
                              hipStream_t stream) {
    const float* x        = (const float*)d_in[0];
    const int*   ei       = (const int*)  d_in[1];
    const float* ea       = (const float*)d_in[2];
    const float* gf       = (const float*)d_in[3];
    const float* W_rel1   = (const float*)d_in[4];
    const float* b1       = (const float*)d_in[5];
    const float* W_root1  = (const float*)d_in[6];
    const float* W_rel2   = (const float*)d_in[7];
    const float* b2       = (const float*)d_in[8];
    const float* W_root2  = (const float*)d_in[9];
    const float* Wg1      = (const float*)d_in[10];
    const float* bg1      = (const float*)d_in[11];
    const float* Wg2      = (const float*)d_in[12];
    const float* bg2      = (const float*)d_in[13];
    const float* Wg3      = (const float*)d_in[14];
    const float* bg3      = (const float*)d_in[15];
    const float* Wo1      = (const float*)d_in[16];
    const float* bo1      = (const float*)d_in[17];
    const float* Wo2      = (const float*)d_in[18];
    const float* bo2      = (const float*)d_in[19];

    float* out   = (float*)d_out;
    _Float16* V  = (_Float16*)d_ws;             // [B, VROW] fp16

    const int B = out_size;                     // 32768
    const int E = in_sizes[1] / 2;

    graph_kernel<<<B / GPB, 128, 0, stream>>>(
        x, ei, ea,
        W_rel1, b1, W_root1, W_rel2, b2, W_root2,
        V, E);

    out_mlp_mfma<<<B / 128, 512, 128 * BTS * sizeof(_Float16), stream>>>(
        V, gf, Wg1, bg1, Wg2, bg2, Wg3, bg3, Wo1, bo1, Wo2, bo2, out);
}